// Round 5
// baseline (363.719 us; speedup 1.0000x reference)
//
#include <hip/hip_runtime.h>
#include <math.h>

#define T 2048
#define HIDDEN 2048
#define NH 16
#define NKV 4
#define HD 128
#define QKV_N 3072   // (16 + 2*4) * 128
#define Q_SIZE 2048  // 16*128
#define KV_SIZE 512  // 4*128

typedef __attribute__((ext_vector_type(8))) short short8;
typedef __attribute__((ext_vector_type(4))) short short4v;
typedef __attribute__((ext_vector_type(4))) float floatx4;

__device__ __forceinline__ unsigned short f2bf(float f) {
    union { float f; unsigned int u; } v; v.f = f;
    unsigned int u = v.u;
    u += 0x7fffu + ((u >> 16) & 1u);   // round-to-nearest-even
    return (unsigned short)(u >> 16);
}
__device__ __forceinline__ float bf2f(unsigned short h) {
    union { unsigned int u; float f; } v; v.u = ((unsigned int)h) << 16;
    return v.f;
}

// async global->LDS, 16B per lane; LDS dest = wave-uniform base + lane*16 (HW adds it)
__device__ __forceinline__ void gload_lds16(const unsigned short* g, unsigned short* l) {
    __builtin_amdgcn_global_load_lds((const __attribute__((address_space(1))) unsigned int*)g,
                                     (__attribute__((address_space(3))) unsigned int*)l, 16, 0, 0);
}

// ---------------- cos/sin tables (mrope sectioning) ----------------
__global__ void prep_cossin(const int* __restrict__ positions,
                            float* __restrict__ cosT, float* __restrict__ sinT) {
    int t = blockIdx.x;
    int j = threadIdx.x;           // 0..63
    int row = (j >= 44) ? 0 : ((j & 1) ? 2 : 1);
    int pos = positions[row * T + t];
    double invf = pow(500000.0, -(double)j / 64.0);
    double ang = (double)pos * invf;
    cosT[t * 64 + j] = (float)cos(ang);
    sinT[t * 64 + j] = (float)sin(ang);
}

// ---------------- fp32 -> bf16 convert ----------------
__global__ __launch_bounds__(256) void convert_f32_bf16(const float* __restrict__ in,
                                                        unsigned short* __restrict__ out, int n) {
    int i = (blockIdx.x * 256 + threadIdx.x) * 4;
    if (i + 3 < n) {
        float4 v = *(const float4*)(in + i);
        out[i]     = f2bf(v.x);
        out[i + 1] = f2bf(v.y);
        out[i + 2] = f2bf(v.z);
        out[i + 3] = f2bf(v.w);
    }
}

// ---------------- transpose fp32 -> bf16 : out[c][r] = in[r][c] ----------------
__global__ __launch_bounds__(256) void transpose_f32_bf16(const float* __restrict__ in,
                                                          unsigned short* __restrict__ out,
                                                          int R, int C) {
    __shared__ float tile[32][33];
    int tx = threadIdx.x, ty = threadIdx.y;          // (32,8)
    int c0 = blockIdx.x * 32, r0 = blockIdx.y * 32;
#pragma unroll
    for (int i = 0; i < 4; ++i)
        tile[ty + i * 8][tx] = in[(long)(r0 + ty + i * 8) * C + c0 + tx];
    __syncthreads();
#pragma unroll
    for (int i = 0; i < 4; ++i)
        out[(long)(c0 + ty + i * 8) * R + r0 + tx] = f2bf(tile[tx][ty + i * 8]);
}

// ---------------- transpose bf16 (batched over z) ----------------
__global__ __launch_bounds__(256) void transpose_bf16(const unsigned short* __restrict__ in,
                                                      unsigned short* __restrict__ out,
                                                      int R, int C) {
    __shared__ unsigned short tile[32][33];
    long zo = (long)blockIdx.z * R * C;
    in += zo; out += zo;
    int tx = threadIdx.x, ty = threadIdx.y;
    int c0 = blockIdx.x * 32, r0 = blockIdx.y * 32;
#pragma unroll
    for (int i = 0; i < 4; ++i)
        tile[ty + i * 8][tx] = in[(long)(r0 + ty + i * 8) * C + c0 + tx];
    __syncthreads();
#pragma unroll
    for (int i = 0; i < 4; ++i)
        out[(long)(c0 + ty + i * 8) * R + r0 + tx] = tile[tx][ty + i * 8];
}

// ---------------- rope + split qkv -> q_bf (pre-scaled), k_bf, v_bf ----------------
__global__ __launch_bounds__(256) void rope_split(const float* __restrict__ qkv,
                                                  const float* __restrict__ cosT,
                                                  const float* __restrict__ sinT,
                                                  unsigned short* __restrict__ qb,
                                                  unsigned short* __restrict__ kb,
                                                  unsigned short* __restrict__ vb) {
    const float scale = 0.08838834764831845f;   // 1/sqrt(128), folded into Q
    int t = blockIdx.x, tid = threadIdx.x;
    const float* row = qkv + (long)t * QKV_N;
    const float* ct = cosT + t * 64;
    const float* st = sinT + t * 64;
    for (int i = tid; i < NH * 64; i += 256) {
        int h = i >> 6, j = i & 63;
        float c = ct[j], s = st[j];
        float x1 = row[h * HD + 2 * j], x2 = row[h * HD + 2 * j + 1];
        qb[(long)t * Q_SIZE + h * HD + 2 * j]     = f2bf((x1 * c - x2 * s) * scale);
        qb[(long)t * Q_SIZE + h * HD + 2 * j + 1] = f2bf((x2 * c + x1 * s) * scale);
    }
    {
        int i = tid;
        int g = i >> 6, j = i & 63;
        float c = ct[j], s = st[j];
        float x1 = row[Q_SIZE + g * HD + 2 * j], x2 = row[Q_SIZE + g * HD + 2 * j + 1];
        kb[(long)t * KV_SIZE + g * HD + 2 * j]     = f2bf(x1 * c - x2 * s);
        kb[(long)t * KV_SIZE + g * HD + 2 * j + 1] = f2bf(x2 * c + x1 * s);
    }
    for (int i = tid; i < KV_SIZE; i += 256) {
        int g = i >> 7, d = i & 127;
        vb[((long)g * T + t) * HD + d] = f2bf(row[Q_SIZE + KV_SIZE + g * HD + d]);
    }
}

// ---------------- GEMM m97-style: C(fp32, MxN) = A(bf16 MxK) * B^T(bf16 NxK) ----------------
// 128x128 tile, 4 waves (2x2 of 64x64), BK=32, global_load_lds width 16, unpadded LDS tiles.
__global__ __launch_bounds__(256) void gemm_bt128(const unsigned short* __restrict__ A,
                                                  const unsigned short* __restrict__ B,
                                                  float* __restrict__ C,
                                                  int K, int ldc) {
    __shared__ __align__(16) unsigned short As[128 * 32];
    __shared__ __align__(16) unsigned short Bs[128 * 32];
    const int tid = threadIdx.x;
    const int wv = tid >> 6;
    const int wr = wv >> 1, wc = wv & 1;
    const int lane = tid & 63;
    const int m = lane & 15, qd = lane >> 4;
    const unsigned short* Ab = A + (long)(blockIdx.x * 128) * K;
    const unsigned short* Bb = B + (long)(blockIdx.y * 128) * K;

    const int srow = lane >> 2;          // 0..15 within wave's 16-row chunk
    const int scol = (lane & 3) * 8;     // shorts

    floatx4 acc[4][4];
#pragma unroll
    for (int i = 0; i < 4; ++i)
#pragma unroll
        for (int j = 0; j < 4; ++j) acc[i][j] = (floatx4){0.f, 0.f, 0.f, 0.f};

    for (int k0 = 0; k0 < K; k0 += 32) {
        __syncthreads();
        gload_lds16(Ab + (long)(wv * 16 + srow) * K + k0 + scol,        &As[wv * 512]);
        gload_lds16(Ab + (long)(64 + wv * 16 + srow) * K + k0 + scol,   &As[2048 + wv * 512]);
        gload_lds16(Bb + (long)(wv * 16 + srow) * K + k0 + scol,        &Bs[wv * 512]);
        gload_lds16(Bb + (long)(64 + wv * 16 + srow) * K + k0 + scol,   &Bs[2048 + wv * 512]);
        __syncthreads();
        short8 a[4], b[4];
#pragma unroll
        for (int i = 0; i < 4; ++i) a[i] = *(const short8*)&As[(wr * 64 + i * 16 + m) * 32 + qd * 8];
#pragma unroll
        for (int j = 0; j < 4; ++j) b[j] = *(const short8*)&Bs[(wc * 64 + j * 16 + m) * 32 + qd * 8];
#pragma unroll
        for (int i = 0; i < 4; ++i)
#pragma unroll
            for (int j = 0; j < 4; ++j)
                acc[i][j] = __builtin_amdgcn_mfma_f32_16x16x32_bf16(a[i], b[j], acc[i][j], 0, 0, 0);
    }

#pragma unroll
    for (int i = 0; i < 4; ++i)
#pragma unroll
        for (int j = 0; j < 4; ++j)
#pragma unroll
            for (int r = 0; r < 4; ++r)
                C[(long)(blockIdx.x * 128 + wr * 64 + i * 16 + qd * 4 + r) * ldc +
                  blockIdx.y * 128 + wc * 64 + j * 16 + m] = acc[i][j][r];
}

// ---------------- flash attention v4: same as v3 but with a real register budget ----------------
// __launch_bounds__(256, 2): 2 waves/EU -> 256 VGPR cap. R4's default budget (76 VGPR) spilled
// the prefetch + accumulators to scratch -> 196 MB HBM writes. ~170 live regs fit under 256.
__global__ __launch_bounds__(256, 2) void flash_attn(const unsigned short* __restrict__ qb,
                                                     const unsigned short* __restrict__ kb,
                                                     const unsigned short* __restrict__ vt,
                                                     float* __restrict__ Opart,
                                                     float* __restrict__ MLpart) {
    __shared__ __align__(16) unsigned short Ks[64 * 136];
    __shared__ __align__(16) unsigned short Vts[128 * 72];
    __shared__ __align__(16) unsigned short Pls[4][16 * 72];

    const int tid = threadIdx.x;
    const int wv = tid >> 6;
    const int lane = tid & 63;
    const int m = lane & 15;
    const int qd = lane >> 4;

    const int bx = blockIdx.x;
    const int h = bx >> 6;
    const int qt = (bx >> 1) & 31;
    const int half = bx & 1;
    const int g = h >> 2;

    const int n = qt + 1;
    const int n0 = (n + 1) >> 1;
    const int jt0 = half ? n0 : 0;
    const int jt1 = half ? n : n0;

    const int q0 = qt * 64;
    const int krow = tid >> 2, kcolb = (tid & 3) * 8;
    const int vrow = tid >> 1, vcolb = (tid & 1) * 8;

    unsigned short* myP = Pls[wv];

    // Q fragments (B-operand rows = q = wv*16+m); Q pre-scaled by 1/sqrt(d)
    short8 aq[4];
#pragma unroll
    for (int kk = 0; kk < 4; ++kk)
        aq[kk] = *(const short8*)(qb + (long)(q0 + wv * 16 + m) * Q_SIZE + h * HD + kk * 32 + qd * 8);

    floatx4 acc_o[8];
#pragma unroll
    for (int nb = 0; nb < 8; ++nb) acc_o[nb] = (floatx4){0.f, 0.f, 0.f, 0.f};
    float mrow = -1e30f, lrow = 0.f;

    if (jt0 < jt1) {
        uint4 kreg[4], vreg[4];
        {
            const unsigned short* kp = kb + (long)(jt0 * 64 + krow) * KV_SIZE + g * HD + kcolb;
#pragma unroll
            for (int c4 = 0; c4 < 4; ++c4) kreg[c4] = *(const uint4*)(kp + c4 * 32);
            const unsigned short* vp = vt + ((long)g * HD + vrow) * T + jt0 * 64 + vcolb;
#pragma unroll
            for (int c4 = 0; c4 < 4; ++c4) vreg[c4] = *(const uint4*)(vp + c4 * 16);
        }
        for (int jt = jt0; jt < jt1; ++jt) {
            if (jt > jt0) __syncthreads();          // LDS readers of prev tile done
#pragma unroll
            for (int c4 = 0; c4 < 4; ++c4) *(uint4*)&Ks[krow * 136 + kcolb + c4 * 32] = kreg[c4];
#pragma unroll
            for (int c4 = 0; c4 < 4; ++c4) *(uint4*)&Vts[vrow * 72 + vcolb + c4 * 16] = vreg[c4];
            __syncthreads();
            if (jt + 1 < jt1) {                     // prefetch next tile (overlaps compute)
                const unsigned short* kp = kb + (long)((jt + 1) * 64 + krow) * KV_SIZE + g * HD + kcolb;
#pragma unroll
                for (int c4 = 0; c4 < 4; ++c4) kreg[c4] = *(const uint4*)(kp + c4 * 32);
                const unsigned short* vp = vt + ((long)g * HD + vrow) * T + (jt + 1) * 64 + vcolb;
#pragma unroll
                for (int c4 = 0; c4 < 4; ++c4) vreg[c4] = *(const uint4*)(vp + c4 * 16);
            }

            // S^T = K Q^T : D rows = keys (c*16+qd*4+r), cols = q (m)
            floatx4 acc_s[4];
#pragma unroll
            for (int c = 0; c < 4; ++c) acc_s[c] = (floatx4){0.f, 0.f, 0.f, 0.f};
#pragma unroll
            for (int kk = 0; kk < 4; ++kk) {
#pragma unroll
                for (int c = 0; c < 4; ++c) {
                    short8 ak = *(const short8*)&Ks[(c * 16 + m) * 136 + kk * 32 + qd * 8];
                    acc_s[c] = __builtin_amdgcn_mfma_f32_16x16x32_bf16(ak, aq[kk], acc_s[c], 0, 0, 0);
                }
            }

            float sv[4][4];
#pragma unroll
            for (int c = 0; c < 4; ++c)
#pragma unroll
                for (int r = 0; r < 4; ++r) sv[c][r] = acc_s[c][r];
            if (jt == qt) {   // diagonal tile: mask key > q
#pragma unroll
                for (int c = 0; c < 4; ++c)
#pragma unroll
                    for (int r = 0; r < 4; ++r)
                        if (c * 16 + qd * 4 + r > wv * 16 + m) sv[c][r] = -1e30f;
            }

            // max over 64 keys: register tree (16) + 2 shuffles across qd lanes
            float mx = sv[0][0];
#pragma unroll
            for (int c = 0; c < 4; ++c)
#pragma unroll
                for (int r = 0; r < 4; ++r) mx = fmaxf(mx, sv[c][r]);
            mx = fmaxf(mx, __shfl_xor(mx, 16));
            mx = fmaxf(mx, __shfl_xor(mx, 32));
            float mnew = fmaxf(mrow, mx);
            float alpha = __expf(mrow - mnew);
            mrow = mnew;

            float pv[4][4];
            float lsum = 0.f;
#pragma unroll
            for (int c = 0; c < 4; ++c)
#pragma unroll
                for (int r = 0; r < 4; ++r) {
                    pv[c][r] = __expf(sv[c][r] - mnew);
                    lsum += pv[c][r];
                }
            lsum += __shfl_xor(lsum, 16);
            lsum += __shfl_xor(lsum, 32);
            lrow = lrow * alpha + lsum;
#pragma unroll
            for (int nb = 0; nb < 8; ++nb)
#pragma unroll
                for (int r = 0; r < 4; ++r) acc_o[nb][r] *= alpha;

            // P: pack 4 bf16 per acc -> per-wave LDS (B-layout rows q=m), then PV
#pragma unroll
            for (int c = 0; c < 4; ++c) {
                short4v pk = {(short)f2bf(pv[c][0]), (short)f2bf(pv[c][1]),
                              (short)f2bf(pv[c][2]), (short)f2bf(pv[c][3])};
                *(short4v*)&myP[m * 72 + c * 16 + qd * 4] = pk;
            }
#pragma unroll
            for (int kk = 0; kk < 2; ++kk) {
                short8 pa = *(const short8*)&myP[m * 72 + kk * 32 + qd * 8];
#pragma unroll
                for (int nb = 0; nb < 8; ++nb) {
                    short8 av = *(const short8*)&Vts[(nb * 16 + m) * 72 + kk * 32 + qd * 8];
                    acc_o[nb] = __builtin_amdgcn_mfma_f32_16x16x32_bf16(av, pa, acc_o[nb], 0, 0, 0);
                }
            }
        }
    }

    // store partials: O^T layout -> Opart[(bx*64 + q_local)*128 + d], fp32 unnormalized
    const long rbase = (long)bx * 64 + wv * 16 + m;
#pragma unroll
    for (int nb = 0; nb < 8; ++nb)
        *(floatx4*)&Opart[rbase * 128 + nb * 16 + qd * 4] = acc_o[nb];
    if (qd == 0) {
        MLpart[rbase * 2]     = mrow;
        MLpart[rbase * 2 + 1] = lrow;
    }
}

// ---------------- combine K-split partials -> ab bf16 [t][h*128+d] ----------------
__global__ __launch_bounds__(256) void attn_combine(const float* __restrict__ Opart,
                                                    const float* __restrict__ MLpart,
                                                    unsigned short* __restrict__ ab) {
    const int tid = threadIdx.x;
    const int q = blockIdx.x * 16 + (tid >> 4);
    const int h = blockIdx.y;
    const int d0 = (tid & 15) * 8;
    const int qt = q >> 6, lr = q & 63;
    const long r0 = ((long)(h * 64 + qt * 2)) * 64 + lr;
    const long r1 = r0 + 64;
    float m0 = MLpart[r0 * 2], l0 = MLpart[r0 * 2 + 1];
    float m1 = MLpart[r1 * 2], l1 = MLpart[r1 * 2 + 1];
    float M = fmaxf(m0, m1);
    float a0 = __expf(m0 - M), a1 = __expf(m1 - M);
    float inv = 1.f / (l0 * a0 + l1 * a1);
    const float* O0 = Opart + r0 * 128 + d0;
    const float* O1 = Opart + r1 * 128 + d0;
    unsigned short outv[8];
#pragma unroll
    for (int j = 0; j < 8; j += 4) {
        float4 x0 = *(const float4*)(O0 + j);
        float4 x1 = *(const float4*)(O1 + j);
        outv[j]     = f2bf((x0.x * a0 + x1.x * a1) * inv);
        outv[j + 1] = f2bf((x0.y * a0 + x1.y * a1) * inv);
        outv[j + 2] = f2bf((x0.z * a0 + x1.z * a1) * inv);
        outv[j + 3] = f2bf((x0.w * a0 + x1.w * a1) * inv);
    }
    *(short8*)&ab[(long)q * Q_SIZE + h * HD + d0] = *(short8*)outv;
}

extern "C" void kernel_launch(void* const* d_in, const int* in_sizes, int n_in,
                              void* d_out, int out_size, void* d_ws, size_t ws_size,
                              hipStream_t stream) {
    const int* positions = (const int*)d_in[0];
    const float* hidden  = (const float*)d_in[1];
    const float* w_qkv   = (const float*)d_in[2];
    const float* w_o     = (const float*)d_in[3];
    float* out = (float*)d_out;

    char* p = (char*)d_ws;
    auto alloc = [&](size_t bytes) { char* r = p; p += (bytes + 255) & ~(size_t)255; return r; };
    float* cosT = (float*)alloc((size_t)T * 64 * 4);
    float* sinT = (float*)alloc((size_t)T * 64 * 4);
    float* qkv  = (float*)alloc((size_t)T * QKV_N * 4);
    unsigned short* hb  = (unsigned short*)alloc((size_t)T * HIDDEN * 2);
    unsigned short* wqt = (unsigned short*)alloc((size_t)QKV_N * HIDDEN * 2);
    unsigned short* wot = (unsigned short*)alloc((size_t)HIDDEN * HIDDEN * 2);
    unsigned short* qb  = (unsigned short*)alloc((size_t)T * Q_SIZE * 2);
    unsigned short* kb  = (unsigned short*)alloc((size_t)T * KV_SIZE * 2);
    unsigned short* vb  = (unsigned short*)alloc((size_t)T * KV_SIZE * 2);
    unsigned short* vt  = (unsigned short*)alloc((size_t)T * KV_SIZE * 2);
    unsigned short* ab  = (unsigned short*)alloc((size_t)T * Q_SIZE * 2);
    float* Opart  = (float*)alloc((size_t)1024 * 64 * 128 * 4);   // 33.5 MB
    float* MLpart = (float*)alloc((size_t)1024 * 64 * 2 * 4);

    dim3 tb(32, 8);
    prep_cossin<<<T, 64, 0, stream>>>(positions, cosT, sinT);
    convert_f32_bf16<<<(T * HIDDEN) / 1024, 256, 0, stream>>>(hidden, hb, T * HIDDEN);
    transpose_f32_bf16<<<dim3(QKV_N / 32, HIDDEN / 32), tb, 0, stream>>>(w_qkv, wqt, HIDDEN, QKV_N);
    transpose_f32_bf16<<<dim3(HIDDEN / 32, HIDDEN / 32), tb, 0, stream>>>(w_o, wot, HIDDEN, HIDDEN);
    // qkv = hidden @ w_qkv (fp32 out)
    gemm_bt128<<<dim3(T / 128, QKV_N / 128), 256, 0, stream>>>(hb, wqt, qkv, HIDDEN, QKV_N);
    rope_split<<<T, 256, 0, stream>>>(qkv, cosT, sinT, qb, kb, vb);
    transpose_bf16<<<dim3(HD / 32, T / 32, NKV), tb, 0, stream>>>(vb, vt, T, HD);
    // fused causal attention, K-split x2 -> partials -> combine -> ab bf16
    flash_attn<<<dim3(1024), 256, 0, stream>>>(qb, kb, vt, Opart, MLpart);
    attn_combine<<<dim3(T / 16, NH), 256, 0, stream>>>(Opart, MLpart, ab);
    // out = attn @ w_o (fp32 out)
    gemm_bt128<<<dim3(T / 128, HIDDEN / 128), 256, 0, stream>>>(ab, wot, out, Q_SIZE, HIDDEN);
}

// Round 6
// 290.509 us; speedup vs baseline: 1.2520x; 1.2520x over previous
//
#include <hip/hip_runtime.h>
#include <math.h>

#define T 2048
#define HIDDEN 2048
#define NH 16
#define NKV 4
#define HD 128
#define QKV_N 3072   // (16 + 2*4) * 128
#define Q_SIZE 2048  // 16*128
#define KV_SIZE 512  // 4*128

typedef __attribute__((ext_vector_type(8))) short short8;
typedef __attribute__((ext_vector_type(4))) short short4v;
typedef __attribute__((ext_vector_type(4))) float floatx4;

__device__ __forceinline__ unsigned short f2bf(float f) {
    union { float f; unsigned int u; } v; v.f = f;
    unsigned int u = v.u;
    u += 0x7fffu + ((u >> 16) & 1u);   // round-to-nearest-even
    return (unsigned short)(u >> 16);
}
__device__ __forceinline__ float bf2f(unsigned short h) {
    union { unsigned int u; float f; } v; v.u = ((unsigned int)h) << 16;
    return v.f;
}

// async global->LDS, 16B per lane; LDS dest = wave-uniform base + lane*16 (HW adds it)
__device__ __forceinline__ void gload_lds16(const unsigned short* g, unsigned short* l) {
    __builtin_amdgcn_global_load_lds((const __attribute__((address_space(1))) unsigned int*)g,
                                     (__attribute__((address_space(3))) unsigned int*)l, 16, 0, 0);
}

// ---------------- cos/sin tables (mrope sectioning) ----------------
__global__ void prep_cossin(const int* __restrict__ positions,
                            float* __restrict__ cosT, float* __restrict__ sinT) {
    int t = blockIdx.x;
    int j = threadIdx.x;           // 0..63
    int row = (j >= 44) ? 0 : ((j & 1) ? 2 : 1);
    int pos = positions[row * T + t];
    double invf = pow(500000.0, -(double)j / 64.0);
    double ang = (double)pos * invf;
    cosT[t * 64 + j] = (float)cos(ang);
    sinT[t * 64 + j] = (float)sin(ang);
}

// ---------------- fp32 -> bf16 convert ----------------
__global__ __launch_bounds__(256) void convert_f32_bf16(const float* __restrict__ in,
                                                        unsigned short* __restrict__ out, int n) {
    int i = (blockIdx.x * 256 + threadIdx.x) * 4;
    if (i + 3 < n) {
        float4 v = *(const float4*)(in + i);
        out[i]     = f2bf(v.x);
        out[i + 1] = f2bf(v.y);
        out[i + 2] = f2bf(v.z);
        out[i + 3] = f2bf(v.w);
    }
}

// ---------------- transpose fp32 -> bf16 : out[c][r] = in[r][c] ----------------
__global__ __launch_bounds__(256) void transpose_f32_bf16(const float* __restrict__ in,
                                                          unsigned short* __restrict__ out,
                                                          int R, int C) {
    __shared__ float tile[32][33];
    int tx = threadIdx.x, ty = threadIdx.y;          // (32,8)
    int c0 = blockIdx.x * 32, r0 = blockIdx.y * 32;
#pragma unroll
    for (int i = 0; i < 4; ++i)
        tile[ty + i * 8][tx] = in[(long)(r0 + ty + i * 8) * C + c0 + tx];
    __syncthreads();
#pragma unroll
    for (int i = 0; i < 4; ++i)
        out[(long)(c0 + ty + i * 8) * R + r0 + tx] = f2bf(tile[tx][ty + i * 8]);
}

// ---------------- transpose bf16 (batched over z) ----------------
__global__ __launch_bounds__(256) void transpose_bf16(const unsigned short* __restrict__ in,
                                                      unsigned short* __restrict__ out,
                                                      int R, int C) {
    __shared__ unsigned short tile[32][33];
    long zo = (long)blockIdx.z * R * C;
    in += zo; out += zo;
    int tx = threadIdx.x, ty = threadIdx.y;
    int c0 = blockIdx.x * 32, r0 = blockIdx.y * 32;
#pragma unroll
    for (int i = 0; i < 4; ++i)
        tile[ty + i * 8][tx] = in[(long)(r0 + ty + i * 8) * C + c0 + tx];
    __syncthreads();
#pragma unroll
    for (int i = 0; i < 4; ++i)
        out[(long)(c0 + ty + i * 8) * R + r0 + tx] = tile[tx][ty + i * 8];
}

// ---------------- rope + split qkv -> q_bf (pre-scaled), k_bf, v_bf ----------------
__global__ __launch_bounds__(256) void rope_split(const float* __restrict__ qkv,
                                                  const float* __restrict__ cosT,
                                                  const float* __restrict__ sinT,
                                                  unsigned short* __restrict__ qb,
                                                  unsigned short* __restrict__ kb,
                                                  unsigned short* __restrict__ vb) {
    const float scale = 0.08838834764831845f;   // 1/sqrt(128), folded into Q
    int t = blockIdx.x, tid = threadIdx.x;
    const float* row = qkv + (long)t * QKV_N;
    const float* ct = cosT + t * 64;
    const float* st = sinT + t * 64;
    for (int i = tid; i < NH * 64; i += 256) {
        int h = i >> 6, j = i & 63;
        float c = ct[j], s = st[j];
        float x1 = row[h * HD + 2 * j], x2 = row[h * HD + 2 * j + 1];
        qb[(long)t * Q_SIZE + h * HD + 2 * j]     = f2bf((x1 * c - x2 * s) * scale);
        qb[(long)t * Q_SIZE + h * HD + 2 * j + 1] = f2bf((x2 * c + x1 * s) * scale);
    }
    {
        int i = tid;
        int g = i >> 6, j = i & 63;
        float c = ct[j], s = st[j];
        float x1 = row[Q_SIZE + g * HD + 2 * j], x2 = row[Q_SIZE + g * HD + 2 * j + 1];
        kb[(long)t * KV_SIZE + g * HD + 2 * j]     = f2bf(x1 * c - x2 * s);
        kb[(long)t * KV_SIZE + g * HD + 2 * j + 1] = f2bf(x2 * c + x1 * s);
    }
    for (int i = tid; i < KV_SIZE; i += 256) {
        int g = i >> 7, d = i & 127;
        vb[((long)g * T + t) * HD + d] = f2bf(row[Q_SIZE + KV_SIZE + g * HD + d]);
    }
}

// ---------------- GEMM m97-style: C(fp32, MxN) = A(bf16 MxK) * B^T(bf16 NxK) ----------------
// 128x128 tile, 4 waves (2x2 of 64x64), BK=32, global_load_lds width 16, unpadded LDS tiles.
__global__ __launch_bounds__(256) void gemm_bt128(const unsigned short* __restrict__ A,
                                                  const unsigned short* __restrict__ B,
                                                  float* __restrict__ C,
                                                  int K, int ldc) {
    __shared__ __align__(16) unsigned short As[128 * 32];
    __shared__ __align__(16) unsigned short Bs[128 * 32];
    const int tid = threadIdx.x;
    const int wv = tid >> 6;
    const int wr = wv >> 1, wc = wv & 1;
    const int lane = tid & 63;
    const int m = lane & 15, qd = lane >> 4;
    const unsigned short* Ab = A + (long)(blockIdx.x * 128) * K;
    const unsigned short* Bb = B + (long)(blockIdx.y * 128) * K;

    const int srow = lane >> 2;          // 0..15 within wave's 16-row chunk
    const int scol = (lane & 3) * 8;     // shorts

    floatx4 acc[4][4];
#pragma unroll
    for (int i = 0; i < 4; ++i)
#pragma unroll
        for (int j = 0; j < 4; ++j) acc[i][j] = (floatx4){0.f, 0.f, 0.f, 0.f};

    for (int k0 = 0; k0 < K; k0 += 32) {
        __syncthreads();
        gload_lds16(Ab + (long)(wv * 16 + srow) * K + k0 + scol,        &As[wv * 512]);
        gload_lds16(Ab + (long)(64 + wv * 16 + srow) * K + k0 + scol,   &As[2048 + wv * 512]);
        gload_lds16(Bb + (long)(wv * 16 + srow) * K + k0 + scol,        &Bs[wv * 512]);
        gload_lds16(Bb + (long)(64 + wv * 16 + srow) * K + k0 + scol,   &Bs[2048 + wv * 512]);
        __syncthreads();
        short8 a[4], b[4];
#pragma unroll
        for (int i = 0; i < 4; ++i) a[i] = *(const short8*)&As[(wr * 64 + i * 16 + m) * 32 + qd * 8];
#pragma unroll
        for (int j = 0; j < 4; ++j) b[j] = *(const short8*)&Bs[(wc * 64 + j * 16 + m) * 32 + qd * 8];
#pragma unroll
        for (int i = 0; i < 4; ++i)
#pragma unroll
            for (int j = 0; j < 4; ++j)
                acc[i][j] = __builtin_amdgcn_mfma_f32_16x16x32_bf16(a[i], b[j], acc[i][j], 0, 0, 0);
    }

#pragma unroll
    for (int i = 0; i < 4; ++i)
#pragma unroll
        for (int j = 0; j < 4; ++j)
#pragma unroll
            for (int r = 0; r < 4; ++r)
                C[(long)(blockIdx.x * 128 + wr * 64 + i * 16 + qd * 4 + r) * ldc +
                  blockIdx.y * 128 + wc * 64 + j * 16 + m] = acc[i][j][r];
}

// ---------------- flash attention v5: async LDS double-buffer, XOR-swizzled tiles --------------
// grid(1024): bx = h*64 + qt*2 + half; block 256 (4 waves), 64 Q-rows, keys K-split in halves.
// Prefetch of tile jt+1 via global_load_lds into buf[cur^1] right after the barrier — zero
// per-thread prefetch registers (R4/R5's 32-reg prefetch state scratch-spilled -> 150 MB HBM).
// K tile 64x128 and V^T tile 128x64 are stored XOR-chunk-swizzled (chunk c of row r holds
// global chunk c^(r&mask)); readers apply the same XOR -> bank-optimal b128 reads, no padding
// (global_load_lds requires contiguous lane*16 destinations).
__global__ __launch_bounds__(256, 2) void flash_attn(const unsigned short* __restrict__ qb,
                                                     const unsigned short* __restrict__ kb,
                                                     const unsigned short* __restrict__ vt,
                                                     float* __restrict__ Opart,
                                                     float* __restrict__ MLpart) {
    __shared__ __align__(16) unsigned short Kbuf[2][64 * 128];
    __shared__ __align__(16) unsigned short Vbuf[2][128 * 64];
    __shared__ __align__(16) unsigned short Pls[4][16 * 72];

    const int tid = threadIdx.x;
    const int wv = tid >> 6;
    const int lane = tid & 63;
    const int m = lane & 15;
    const int qd = lane >> 4;

    const int bx = blockIdx.x;
    const int h = bx >> 6;
    const int qt = (bx >> 1) & 31;
    const int half = bx & 1;
    const int g = h >> 2;

    const int n = qt + 1;
    const int n0 = (n + 1) >> 1;
    const int jt0 = half ? n0 : 0;
    const int jt1 = half ? n : n0;

    const int q0 = qt * 64;
    unsigned short* myP = Pls[wv];

    // Q fragments (B-operand rows = q = wv*16+m); Q pre-scaled by 1/sqrt(d)
    short8 aq[4];
#pragma unroll
    for (int kk = 0; kk < 4; ++kk)
        aq[kk] = *(const short8*)(qb + (long)(q0 + wv * 16 + m) * Q_SIZE + h * HD + kk * 32 + qd * 8);

    floatx4 acc_o[8];
#pragma unroll
    for (int nb = 0; nb < 8; ++nb) acc_o[nb] = (floatx4){0.f, 0.f, 0.f, 0.f};
    float mrow = -1e30f, lrow = 0.f;

    if (jt0 < jt1) {
        // ---- stage first tile into buf 0 (async) ----
#pragma unroll
        for (int i = 0; i < 4; ++i) {   // K: 64 rows x 16 chunks, swizzle c^(r&15)
            int s = i * 256 + tid;
            int r = s >> 4, c = (s & 15) ^ (r & 15);
            gload_lds16(kb + (long)(jt0 * 64 + r) * KV_SIZE + g * HD + c * 8,
                        &Kbuf[0][i * 2048 + wv * 512]);
        }
#pragma unroll
        for (int i = 0; i < 4; ++i) {   // V^T: 128 rows x 8 chunks, swizzle c^(r&7)
            int s = i * 256 + tid;
            int r = s >> 3, c = (s & 7) ^ (r & 7);
            gload_lds16(vt + ((long)g * HD + r) * T + jt0 * 64 + c * 8,
                        &Vbuf[0][i * 2048 + wv * 512]);
        }

        int cur = 0;
        for (int jt = jt0; jt < jt1; ++jt) {
            __syncthreads();   // drains vmcnt: buf[cur] ready; prev readers of buf[cur^1] done

            if (jt + 1 < jt1) {   // async prefetch next tile into buf[cur^1]; overlaps compute
#pragma unroll
                for (int i = 0; i < 4; ++i) {
                    int s = i * 256 + tid;
                    int r = s >> 4, c = (s & 15) ^ (r & 15);
                    gload_lds16(kb + (long)((jt + 1) * 64 + r) * KV_SIZE + g * HD + c * 8,
                                &Kbuf[cur ^ 1][i * 2048 + wv * 512]);
                }
#pragma unroll
                for (int i = 0; i < 4; ++i) {
                    int s = i * 256 + tid;
                    int r = s >> 3, c = (s & 7) ^ (r & 7);
                    gload_lds16(vt + ((long)g * HD + r) * T + (jt + 1) * 64 + c * 8,
                                &Vbuf[cur ^ 1][i * 2048 + wv * 512]);
                }
            }

            // S^T = K Q^T : D rows = keys (c*16+qd*4+r), cols = q (m)
            floatx4 acc_s[4];
#pragma unroll
            for (int c = 0; c < 4; ++c) acc_s[c] = (floatx4){0.f, 0.f, 0.f, 0.f};
#pragma unroll
            for (int kk = 0; kk < 4; ++kk) {
#pragma unroll
                for (int c = 0; c < 4; ++c) {
                    short8 ak = *(const short8*)&Kbuf[cur][(c * 16 + m) * 128 +
                                                           (((4 * kk + qd) ^ m) * 8)];
                    acc_s[c] = __builtin_amdgcn_mfma_f32_16x16x32_bf16(ak, aq[kk], acc_s[c], 0, 0, 0);
                }
            }

            float sv[4][4];
#pragma unroll
            for (int c = 0; c < 4; ++c)
#pragma unroll
                for (int r = 0; r < 4; ++r) sv[c][r] = acc_s[c][r];
            if (jt == qt) {   // diagonal tile: mask key > q
#pragma unroll
                for (int c = 0; c < 4; ++c)
#pragma unroll
                    for (int r = 0; r < 4; ++r)
                        if (c * 16 + qd * 4 + r > wv * 16 + m) sv[c][r] = -1e30f;
            }

            // max over 64 keys: register tree (16) + 2 shuffles across qd lanes
            float mx = sv[0][0];
#pragma unroll
            for (int c = 0; c < 4; ++c)
#pragma unroll
                for (int r = 0; r < 4; ++r) mx = fmaxf(mx, sv[c][r]);
            mx = fmaxf(mx, __shfl_xor(mx, 16));
            mx = fmaxf(mx, __shfl_xor(mx, 32));
            float mnew = fmaxf(mrow, mx);
            float alpha = __expf(mrow - mnew);
            mrow = mnew;

            float pv[4][4];
            float lsum = 0.f;
#pragma unroll
            for (int c = 0; c < 4; ++c)
#pragma unroll
                for (int r = 0; r < 4; ++r) {
                    pv[c][r] = __expf(sv[c][r] - mnew);
                    lsum += pv[c][r];
                }
            lsum += __shfl_xor(lsum, 16);
            lsum += __shfl_xor(lsum, 32);
            lrow = lrow * alpha + lsum;
#pragma unroll
            for (int nb = 0; nb < 8; ++nb)
#pragma unroll
                for (int r = 0; r < 4; ++r) acc_o[nb][r] *= alpha;

            // P: pack 4 bf16 per acc -> per-wave LDS (B-layout rows q=m), then PV
#pragma unroll
            for (int c = 0; c < 4; ++c) {
                short4v pk = {(short)f2bf(pv[c][0]), (short)f2bf(pv[c][1]),
                              (short)f2bf(pv[c][2]), (short)f2bf(pv[c][3])};
                *(short4v*)&myP[m * 72 + c * 16 + qd * 4] = pk;
            }
#pragma unroll
            for (int kk = 0; kk < 2; ++kk) {
                short8 pa = *(const short8*)&myP[m * 72 + kk * 32 + qd * 8];
#pragma unroll
                for (int nb = 0; nb < 8; ++nb) {
                    short8 av = *(const short8*)&Vbuf[cur][(nb * 16 + m) * 64 +
                                                           (((4 * kk + qd) ^ (m & 7)) * 8)];
                    acc_o[nb] = __builtin_amdgcn_mfma_f32_16x16x32_bf16(av, pa, acc_o[nb], 0, 0, 0);
                }
            }

            cur ^= 1;
        }
    }

    // store partials: O^T layout -> Opart[(bx*64 + q_local)*128 + d], fp32 unnormalized
    const long rbase = (long)bx * 64 + wv * 16 + m;
#pragma unroll
    for (int nb = 0; nb < 8; ++nb)
        *(floatx4*)&Opart[rbase * 128 + nb * 16 + qd * 4] = acc_o[nb];
    if (qd == 0) {
        MLpart[rbase * 2]     = mrow;
        MLpart[rbase * 2 + 1] = lrow;
    }
}

// ---------------- combine K-split partials -> ab bf16 [t][h*128+d] ----------------
__global__ __launch_bounds__(256) void attn_combine(const float* __restrict__ Opart,
                                                    const float* __restrict__ MLpart,
                                                    unsigned short* __restrict__ ab) {
    const int tid = threadIdx.x;
    const int q = blockIdx.x * 16 + (tid >> 4);
    const int h = blockIdx.y;
    const int d0 = (tid & 15) * 8;
    const int qt = q >> 6, lr = q & 63;
    const long r0 = ((long)(h * 64 + qt * 2)) * 64 + lr;
    const long r1 = r0 + 64;
    float m0 = MLpart[r0 * 2], l0 = MLpart[r0 * 2 + 1];
    float m1 = MLpart[r1 * 2], l1 = MLpart[r1 * 2 + 1];
    float M = fmaxf(m0, m1);
    float a0 = __expf(m0 - M), a1 = __expf(m1 - M);
    float inv = 1.f / (l0 * a0 + l1 * a1);
    const float* O0 = Opart + r0 * 128 + d0;
    const float* O1 = Opart + r1 * 128 + d0;
    unsigned short outv[8];
#pragma unroll
    for (int j = 0; j < 8; j += 4) {
        float4 x0 = *(const float4*)(O0 + j);
        float4 x1 = *(const float4*)(O1 + j);
        outv[j]     = f2bf((x0.x * a0 + x1.x * a1) * inv);
        outv[j + 1] = f2bf((x0.y * a0 + x1.y * a1) * inv);
        outv[j + 2] = f2bf((x0.z * a0 + x1.z * a1) * inv);
        outv[j + 3] = f2bf((x0.w * a0 + x1.w * a1) * inv);
    }
    *(short8*)&ab[(long)q * Q_SIZE + h * HD + d0] = *(short8*)outv;
}

extern "C" void kernel_launch(void* const* d_in, const int* in_sizes, int n_in,
                              void* d_out, int out_size, void* d_ws, size_t ws_size,
                              hipStream_t stream) {
    const int* positions = (const int*)d_in[0];
    const float* hidden  = (const float*)d_in[1];
    const float* w_qkv   = (const float*)d_in[2];
    const float* w_o     = (const float*)d_in[3];
    float* out = (float*)d_out;

    char* p = (char*)d_ws;
    auto alloc = [&](size_t bytes) { char* r = p; p += (bytes + 255) & ~(size_t)255; return r; };
    float* cosT = (float*)alloc((size_t)T * 64 * 4);
    float* sinT = (float*)alloc((size_t)T * 64 * 4);
    float* qkv  = (float*)alloc((size_t)T * QKV_N * 4);
    unsigned short* hb  = (unsigned short*)alloc((size_t)T * HIDDEN * 2);
    unsigned short* wqt = (unsigned short*)alloc((size_t)QKV_N * HIDDEN * 2);
    unsigned short* wot = (unsigned short*)alloc((size_t)HIDDEN * HIDDEN * 2);
    unsigned short* qb  = (unsigned short*)alloc((size_t)T * Q_SIZE * 2);
    unsigned short* kb  = (unsigned short*)alloc((size_t)T * KV_SIZE * 2);
    unsigned short* vb  = (unsigned short*)alloc((size_t)T * KV_SIZE * 2);
    unsigned short* vt  = (unsigned short*)alloc((size_t)T * KV_SIZE * 2);
    unsigned short* ab  = (unsigned short*)alloc((size_t)T * Q_SIZE * 2);
    float* Opart  = (float*)alloc((size_t)1024 * 64 * 128 * 4);   // 33.5 MB
    float* MLpart = (float*)alloc((size_t)1024 * 64 * 2 * 4);

    dim3 tb(32, 8);
    prep_cossin<<<T, 64, 0, stream>>>(positions, cosT, sinT);
    convert_f32_bf16<<<(T * HIDDEN) / 1024, 256, 0, stream>>>(hidden, hb, T * HIDDEN);
    transpose_f32_bf16<<<dim3(QKV_N / 32, HIDDEN / 32), tb, 0, stream>>>(w_qkv, wqt, HIDDEN, QKV_N);
    transpose_f32_bf16<<<dim3(HIDDEN / 32, HIDDEN / 32), tb, 0, stream>>>(w_o, wot, HIDDEN, HIDDEN);
    // qkv = hidden @ w_qkv (fp32 out)
    gemm_bt128<<<dim3(T / 128, QKV_N / 128), 256, 0, stream>>>(hb, wqt, qkv, HIDDEN, QKV_N);
    rope_split<<<T, 256, 0, stream>>>(qkv, cosT, sinT, qb, kb, vb);
    transpose_bf16<<<dim3(HD / 32, T / 32, NKV), tb, 0, stream>>>(vb, vt, T, HD);
    // fused causal attention, K-split x2 -> partials -> combine -> ab bf16
    flash_attn<<<dim3(1024), 256, 0, stream>>>(qb, kb, vt, Opart, MLpart);
    attn_combine<<<dim3(T / 16, NH), 256, 0, stream>>>(Opart, MLpart, ab);
    // out = attn @ w_o (fp32 out)
    gemm_bt128<<<dim3(T / 128, HIDDEN / 128), 256, 0, stream>>>(ab, wot, out, Q_SIZE, HIDDEN);
}

// Round 7
// 280.437 us; speedup vs baseline: 1.2970x; 1.0359x over previous
//
#include <hip/hip_runtime.h>
#include <math.h>

#define T 2048
#define HIDDEN 2048
#define NH 16
#define NKV 4
#define HD 128
#define QKV_N 3072   // (16 + 2*4) * 128
#define Q_SIZE 2048  // 16*128
#define KV_SIZE 512  // 4*128

typedef __attribute__((ext_vector_type(8))) short short8;
typedef __attribute__((ext_vector_type(4))) short short4v;
typedef __attribute__((ext_vector_type(4))) float floatx4;

__device__ __forceinline__ unsigned short f2bf(float f) {
    union { float f; unsigned int u; } v; v.f = f;
    unsigned int u = v.u;
    u += 0x7fffu + ((u >> 16) & 1u);   // round-to-nearest-even
    return (unsigned short)(u >> 16);
}
__device__ __forceinline__ float bf2f(unsigned short h) {
    union { unsigned int u; float f; } v; v.u = ((unsigned int)h) << 16;
    return v.f;
}

// async global->LDS, 16B per lane; LDS dest = wave-uniform base + lane*16 (HW adds it)
__device__ __forceinline__ void gload_lds16(const unsigned short* g, unsigned short* l) {
    __builtin_amdgcn_global_load_lds((const __attribute__((address_space(1))) unsigned int*)g,
                                     (__attribute__((address_space(3))) unsigned int*)l, 16, 0, 0);
}

// ---------------- cos/sin tables (mrope sectioning) ----------------
__global__ void prep_cossin(const int* __restrict__ positions,
                            float* __restrict__ cosT, float* __restrict__ sinT) {
    int t = blockIdx.x;
    int j = threadIdx.x;           // 0..63
    int row = (j >= 44) ? 0 : ((j & 1) ? 2 : 1);
    int pos = positions[row * T + t];
    double invf = pow(500000.0, -(double)j / 64.0);
    double ang = (double)pos * invf;
    cosT[t * 64 + j] = (float)cos(ang);
    sinT[t * 64 + j] = (float)sin(ang);
}

// ---------------- fp32 -> bf16 convert ----------------
__global__ __launch_bounds__(256) void convert_f32_bf16(const float* __restrict__ in,
                                                        unsigned short* __restrict__ out, int n) {
    int i = (blockIdx.x * 256 + threadIdx.x) * 4;
    if (i + 3 < n) {
        float4 v = *(const float4*)(in + i);
        out[i]     = f2bf(v.x);
        out[i + 1] = f2bf(v.y);
        out[i + 2] = f2bf(v.z);
        out[i + 3] = f2bf(v.w);
    }
}

// ---------------- transpose fp32 -> bf16 : out[c][r] = in[r][c] ----------------
__global__ __launch_bounds__(256) void transpose_f32_bf16(const float* __restrict__ in,
                                                          unsigned short* __restrict__ out,
                                                          int R, int C) {
    __shared__ float tile[32][33];
    int tx = threadIdx.x, ty = threadIdx.y;          // (32,8)
    int c0 = blockIdx.x * 32, r0 = blockIdx.y * 32;
#pragma unroll
    for (int i = 0; i < 4; ++i)
        tile[ty + i * 8][tx] = in[(long)(r0 + ty + i * 8) * C + c0 + tx];
    __syncthreads();
#pragma unroll
    for (int i = 0; i < 4; ++i)
        out[(long)(c0 + ty + i * 8) * R + r0 + tx] = f2bf(tile[tx][ty + i * 8]);
}

// ---------------- transpose bf16 (batched over z) ----------------
__global__ __launch_bounds__(256) void transpose_bf16(const unsigned short* __restrict__ in,
                                                      unsigned short* __restrict__ out,
                                                      int R, int C) {
    __shared__ unsigned short tile[32][33];
    long zo = (long)blockIdx.z * R * C;
    in += zo; out += zo;
    int tx = threadIdx.x, ty = threadIdx.y;
    int c0 = blockIdx.x * 32, r0 = blockIdx.y * 32;
#pragma unroll
    for (int i = 0; i < 4; ++i)
        tile[ty + i * 8][tx] = in[(long)(r0 + ty + i * 8) * C + c0 + tx];
    __syncthreads();
#pragma unroll
    for (int i = 0; i < 4; ++i)
        out[(long)(c0 + ty + i * 8) * R + r0 + tx] = tile[tx][ty + i * 8];
}

// ---------------- qkv GEMM, double-buffered async, rope fused in epilogue ----------------
// C = hb(2048xK) * wqt^T(3072xK); per-block column range is uniformly q (by<16),
// k (16<=by<20) or v (by>=20) since 2048/2560 are multiples of 128.
// Rope: pairs are adjacent columns -> partner via __shfl_xor(val,1).
__global__ __launch_bounds__(256) void gemm_qkv(const unsigned short* __restrict__ A,
                                                const unsigned short* __restrict__ B,
                                                const float* __restrict__ cosT,
                                                const float* __restrict__ sinT,
                                                unsigned short* __restrict__ qb,
                                                unsigned short* __restrict__ kb,
                                                unsigned short* __restrict__ vb) {
    __shared__ __align__(16) unsigned short As[2][128 * 32];
    __shared__ __align__(16) unsigned short Bs[2][128 * 32];
    const int K = HIDDEN;
    const int tid = threadIdx.x;
    const int wv = tid >> 6;
    const int wr = wv >> 1, wc = wv & 1;
    const int lane = tid & 63;
    const int m = lane & 15, qd = lane >> 4;
    const unsigned short* Ab = A + (long)(blockIdx.x * 128) * K;
    const unsigned short* Bb = B + (long)(blockIdx.y * 128) * K;
    const int srow = lane >> 2;
    const int scol = (lane & 3) * 8;

    floatx4 acc[4][4];
#pragma unroll
    for (int i = 0; i < 4; ++i)
#pragma unroll
        for (int j = 0; j < 4; ++j) acc[i][j] = (floatx4){0.f, 0.f, 0.f, 0.f};

#define QKV_STAGE(buf, k0)                                                              \
    do {                                                                                \
        gload_lds16(Ab + (long)(wv * 16 + srow) * K + (k0) + scol,      &As[buf][wv * 512]);        \
        gload_lds16(Ab + (long)(64 + wv * 16 + srow) * K + (k0) + scol, &As[buf][2048 + wv * 512]); \
        gload_lds16(Bb + (long)(wv * 16 + srow) * K + (k0) + scol,      &Bs[buf][wv * 512]);        \
        gload_lds16(Bb + (long)(64 + wv * 16 + srow) * K + (k0) + scol, &Bs[buf][2048 + wv * 512]); \
    } while (0)

    QKV_STAGE(0, 0);
    int cur = 0;
    for (int k0 = 0; k0 < K; k0 += 32) {
        __syncthreads();                       // buf[cur] landed; prev readers of buf[cur^1] done
        if (k0 + 32 < K) QKV_STAGE(cur ^ 1, k0 + 32);
        short8 a[4], b[4];
#pragma unroll
        for (int i = 0; i < 4; ++i) a[i] = *(const short8*)&As[cur][(wr * 64 + i * 16 + m) * 32 + qd * 8];
#pragma unroll
        for (int j = 0; j < 4; ++j) b[j] = *(const short8*)&Bs[cur][(wc * 64 + j * 16 + m) * 32 + qd * 8];
#pragma unroll
        for (int i = 0; i < 4; ++i)
#pragma unroll
            for (int j = 0; j < 4; ++j)
                acc[i][j] = __builtin_amdgcn_mfma_f32_16x16x32_bf16(a[i], b[j], acc[i][j], 0, 0, 0);
        cur ^= 1;
    }
#undef QKV_STAGE

    const int by = blockIdx.y;
    if (by < 20) {
        // rope path (q: by<16, k: 16..19)
        const float sgn = (m & 1) ? 1.f : -1.f;
        const float qscale = 0.08838834764831845f;   // 1/sqrt(128)
#pragma unroll
        for (int i = 0; i < 4; ++i) {
#pragma unroll
            for (int r = 0; r < 4; ++r) {
                const int t = blockIdx.x * 128 + wr * 64 + i * 16 + qd * 4 + r;
                const float* ct = cosT + t * 64;
                const float* st = sinT + t * 64;
#pragma unroll
                for (int j = 0; j < 4; ++j) {
                    const int cq = wc * 64 + j * 16 + m;    // col within 128-span (= col&127)
                    const int j2 = cq >> 1;
                    float val = acc[i][j][r];
                    float prt = __shfl_xor(val, 1);
                    float o = val * ct[j2] + sgn * prt * st[j2];
                    const int col = by * 128 + cq;
                    if (by < 16) qb[(long)t * Q_SIZE + col] = f2bf(o * qscale);
                    else         kb[(long)t * KV_SIZE + (col - 2048)] = f2bf(o);
                }
            }
        }
    } else {
        // v path: vb[g][t][d], g = by-20, d = cq
        const int g = by - 20;
#pragma unroll
        for (int i = 0; i < 4; ++i)
#pragma unroll
            for (int j = 0; j < 4; ++j) {
                const int d = wc * 64 + j * 16 + m;
#pragma unroll
                for (int r = 0; r < 4; ++r) {
                    const int t = blockIdx.x * 128 + wr * 64 + i * 16 + qd * 4 + r;
                    vb[((long)g * T + t) * HD + d] = f2bf(acc[i][j][r]);
                }
            }
    }
}

// ---------------- out GEMM, double-buffered async: C(fp32) = A * B^T ----------------
__global__ __launch_bounds__(256) void gemm_out(const unsigned short* __restrict__ A,
                                                const unsigned short* __restrict__ B,
                                                float* __restrict__ C,
                                                int K, int ldc) {
    __shared__ __align__(16) unsigned short As[2][128 * 32];
    __shared__ __align__(16) unsigned short Bs[2][128 * 32];
    const int tid = threadIdx.x;
    const int wv = tid >> 6;
    const int wr = wv >> 1, wc = wv & 1;
    const int lane = tid & 63;
    const int m = lane & 15, qd = lane >> 4;
    const unsigned short* Ab = A + (long)(blockIdx.x * 128) * K;
    const unsigned short* Bb = B + (long)(blockIdx.y * 128) * K;
    const int srow = lane >> 2;
    const int scol = (lane & 3) * 8;

    floatx4 acc[4][4];
#pragma unroll
    for (int i = 0; i < 4; ++i)
#pragma unroll
        for (int j = 0; j < 4; ++j) acc[i][j] = (floatx4){0.f, 0.f, 0.f, 0.f};

#define OUT_STAGE(buf, k0)                                                              \
    do {                                                                                \
        gload_lds16(Ab + (long)(wv * 16 + srow) * K + (k0) + scol,      &As[buf][wv * 512]);        \
        gload_lds16(Ab + (long)(64 + wv * 16 + srow) * K + (k0) + scol, &As[buf][2048 + wv * 512]); \
        gload_lds16(Bb + (long)(wv * 16 + srow) * K + (k0) + scol,      &Bs[buf][wv * 512]);        \
        gload_lds16(Bb + (long)(64 + wv * 16 + srow) * K + (k0) + scol, &Bs[buf][2048 + wv * 512]); \
    } while (0)

    OUT_STAGE(0, 0);
    int cur = 0;
    for (int k0 = 0; k0 < K; k0 += 32) {
        __syncthreads();
        if (k0 + 32 < K) OUT_STAGE(cur ^ 1, k0 + 32);
        short8 a[4], b[4];
#pragma unroll
        for (int i = 0; i < 4; ++i) a[i] = *(const short8*)&As[cur][(wr * 64 + i * 16 + m) * 32 + qd * 8];
#pragma unroll
        for (int j = 0; j < 4; ++j) b[j] = *(const short8*)&Bs[cur][(wc * 64 + j * 16 + m) * 32 + qd * 8];
#pragma unroll
        for (int i = 0; i < 4; ++i)
#pragma unroll
            for (int j = 0; j < 4; ++j)
                acc[i][j] = __builtin_amdgcn_mfma_f32_16x16x32_bf16(a[i], b[j], acc[i][j], 0, 0, 0);
        cur ^= 1;
    }
#undef OUT_STAGE

#pragma unroll
    for (int i = 0; i < 4; ++i)
#pragma unroll
        for (int j = 0; j < 4; ++j)
#pragma unroll
            for (int r = 0; r < 4; ++r)
                C[(long)(blockIdx.x * 128 + wr * 64 + i * 16 + qd * 4 + r) * ldc +
                  blockIdx.y * 128 + wc * 64 + j * 16 + m] = acc[i][j][r];
}

// ---------------- flash attention v5: async LDS double-buffer, XOR-swizzled tiles --------------
__global__ __launch_bounds__(256, 2) void flash_attn(const unsigned short* __restrict__ qb,
                                                     const unsigned short* __restrict__ kb,
                                                     const unsigned short* __restrict__ vt,
                                                     float* __restrict__ Opart,
                                                     float* __restrict__ MLpart) {
    __shared__ __align__(16) unsigned short Kbuf[2][64 * 128];
    __shared__ __align__(16) unsigned short Vbuf[2][128 * 64];
    __shared__ __align__(16) unsigned short Pls[4][16 * 72];

    const int tid = threadIdx.x;
    const int wv = tid >> 6;
    const int lane = tid & 63;
    const int m = lane & 15;
    const int qd = lane >> 4;

    const int bx = blockIdx.x;
    const int h = bx >> 6;
    const int qt = (bx >> 1) & 31;
    const int half = bx & 1;
    const int g = h >> 2;

    const int n = qt + 1;
    const int n0 = (n + 1) >> 1;
    const int jt0 = half ? n0 : 0;
    const int jt1 = half ? n : n0;

    const int q0 = qt * 64;
    unsigned short* myP = Pls[wv];

    short8 aq[4];
#pragma unroll
    for (int kk = 0; kk < 4; ++kk)
        aq[kk] = *(const short8*)(qb + (long)(q0 + wv * 16 + m) * Q_SIZE + h * HD + kk * 32 + qd * 8);

    floatx4 acc_o[8];
#pragma unroll
    for (int nb = 0; nb < 8; ++nb) acc_o[nb] = (floatx4){0.f, 0.f, 0.f, 0.f};
    float mrow = -1e30f, lrow = 0.f;

    if (jt0 < jt1) {
#pragma unroll
        for (int i = 0; i < 4; ++i) {   // K: 64 rows x 16 chunks, swizzle c^(r&15)
            int s = i * 256 + tid;
            int r = s >> 4, c = (s & 15) ^ (r & 15);
            gload_lds16(kb + (long)(jt0 * 64 + r) * KV_SIZE + g * HD + c * 8,
                        &Kbuf[0][i * 2048 + wv * 512]);
        }
#pragma unroll
        for (int i = 0; i < 4; ++i) {   // V^T: 128 rows x 8 chunks, swizzle c^(r&7)
            int s = i * 256 + tid;
            int r = s >> 3, c = (s & 7) ^ (r & 7);
            gload_lds16(vt + ((long)g * HD + r) * T + jt0 * 64 + c * 8,
                        &Vbuf[0][i * 2048 + wv * 512]);
        }

        int cur = 0;
        for (int jt = jt0; jt < jt1; ++jt) {
            __syncthreads();

            if (jt + 1 < jt1) {
#pragma unroll
                for (int i = 0; i < 4; ++i) {
                    int s = i * 256 + tid;
                    int r = s >> 4, c = (s & 15) ^ (r & 15);
                    gload_lds16(kb + (long)((jt + 1) * 64 + r) * KV_SIZE + g * HD + c * 8,
                                &Kbuf[cur ^ 1][i * 2048 + wv * 512]);
                }
#pragma unroll
                for (int i = 0; i < 4; ++i) {
                    int s = i * 256 + tid;
                    int r = s >> 3, c = (s & 7) ^ (r & 7);
                    gload_lds16(vt + ((long)g * HD + r) * T + (jt + 1) * 64 + c * 8,
                                &Vbuf[cur ^ 1][i * 2048 + wv * 512]);
                }
            }

            floatx4 acc_s[4];
#pragma unroll
            for (int c = 0; c < 4; ++c) acc_s[c] = (floatx4){0.f, 0.f, 0.f, 0.f};
#pragma unroll
            for (int kk = 0; kk < 4; ++kk) {
#pragma unroll
                for (int c = 0; c < 4; ++c) {
                    short8 ak = *(const short8*)&Kbuf[cur][(c * 16 + m) * 128 +
                                                           (((4 * kk + qd) ^ m) * 8)];
                    acc_s[c] = __builtin_amdgcn_mfma_f32_16x16x32_bf16(ak, aq[kk], acc_s[c], 0, 0, 0);
                }
            }

            float sv[4][4];
#pragma unroll
            for (int c = 0; c < 4; ++c)
#pragma unroll
                for (int r = 0; r < 4; ++r) sv[c][r] = acc_s[c][r];
            if (jt == qt) {
#pragma unroll
                for (int c = 0; c < 4; ++c)
#pragma unroll
                    for (int r = 0; r < 4; ++r)
                        if (c * 16 + qd * 4 + r > wv * 16 + m) sv[c][r] = -1e30f;
            }

            float mx = sv[0][0];
#pragma unroll
            for (int c = 0; c < 4; ++c)
#pragma unroll
                for (int r = 0; r < 4; ++r) mx = fmaxf(mx, sv[c][r]);
            mx = fmaxf(mx, __shfl_xor(mx, 16));
            mx = fmaxf(mx, __shfl_xor(mx, 32));
            float mnew = fmaxf(mrow, mx);
            float alpha = __expf(mrow - mnew);
            mrow = mnew;

            float pv[4][4];
            float lsum = 0.f;
#pragma unroll
            for (int c = 0; c < 4; ++c)
#pragma unroll
                for (int r = 0; r < 4; ++r) {
                    pv[c][r] = __expf(sv[c][r] - mnew);
                    lsum += pv[c][r];
                }
            lsum += __shfl_xor(lsum, 16);
            lsum += __shfl_xor(lsum, 32);
            lrow = lrow * alpha + lsum;
#pragma unroll
            for (int nb = 0; nb < 8; ++nb)
#pragma unroll
                for (int r = 0; r < 4; ++r) acc_o[nb][r] *= alpha;

#pragma unroll
            for (int c = 0; c < 4; ++c) {
                short4v pk = {(short)f2bf(pv[c][0]), (short)f2bf(pv[c][1]),
                              (short)f2bf(pv[c][2]), (short)f2bf(pv[c][3])};
                *(short4v*)&myP[m * 72 + c * 16 + qd * 4] = pk;
            }
#pragma unroll
            for (int kk = 0; kk < 2; ++kk) {
                short8 pa = *(const short8*)&myP[m * 72 + kk * 32 + qd * 8];
#pragma unroll
                for (int nb = 0; nb < 8; ++nb) {
                    short8 av = *(const short8*)&Vbuf[cur][(nb * 16 + m) * 64 +
                                                           (((4 * kk + qd) ^ (m & 7)) * 8)];
                    acc_o[nb] = __builtin_amdgcn_mfma_f32_16x16x32_bf16(av, pa, acc_o[nb], 0, 0, 0);
                }
            }

            cur ^= 1;
        }
    }

    const long rbase = (long)bx * 64 + wv * 16 + m;
#pragma unroll
    for (int nb = 0; nb < 8; ++nb)
        *(floatx4*)&Opart[rbase * 128 + nb * 16 + qd * 4] = acc_o[nb];
    if (qd == 0) {
        MLpart[rbase * 2]     = mrow;
        MLpart[rbase * 2 + 1] = lrow;
    }
}

// ---------------- combine K-split partials -> ab bf16 [t][h*128+d] ----------------
__global__ __launch_bounds__(256) void attn_combine(const float* __restrict__ Opart,
                                                    const float* __restrict__ MLpart,
                                                    unsigned short* __restrict__ ab) {
    const int tid = threadIdx.x;
    const int q = blockIdx.x * 16 + (tid >> 4);
    const int h = blockIdx.y;
    const int d0 = (tid & 15) * 8;
    const int qt = q >> 6, lr = q & 63;
    const long r0 = ((long)(h * 64 + qt * 2)) * 64 + lr;
    const long r1 = r0 + 64;
    float m0 = MLpart[r0 * 2], l0 = MLpart[r0 * 2 + 1];
    float m1 = MLpart[r1 * 2], l1 = MLpart[r1 * 2 + 1];
    float M = fmaxf(m0, m1);
    float a0 = __expf(m0 - M), a1 = __expf(m1 - M);
    float inv = 1.f / (l0 * a0 + l1 * a1);
    const float* O0 = Opart + r0 * 128 + d0;
    const float* O1 = Opart + r1 * 128 + d0;
    unsigned short outv[8];
#pragma unroll
    for (int j = 0; j < 8; j += 4) {
        float4 x0 = *(const float4*)(O0 + j);
        float4 x1 = *(const float4*)(O1 + j);
        outv[j]     = f2bf((x0.x * a0 + x1.x * a1) * inv);
        outv[j + 1] = f2bf((x0.y * a0 + x1.y * a1) * inv);
        outv[j + 2] = f2bf((x0.z * a0 + x1.z * a1) * inv);
        outv[j + 3] = f2bf((x0.w * a0 + x1.w * a1) * inv);
    }
    *(short8*)&ab[(long)q * Q_SIZE + h * HD + d0] = *(short8*)outv;
}

extern "C" void kernel_launch(void* const* d_in, const int* in_sizes, int n_in,
                              void* d_out, int out_size, void* d_ws, size_t ws_size,
                              hipStream_t stream) {
    const int* positions = (const int*)d_in[0];
    const float* hidden  = (const float*)d_in[1];
    const float* w_qkv   = (const float*)d_in[2];
    const float* w_o     = (const float*)d_in[3];
    float* out = (float*)d_out;

    char* p = (char*)d_ws;
    auto alloc = [&](size_t bytes) { char* r = p; p += (bytes + 255) & ~(size_t)255; return r; };
    float* cosT = (float*)alloc((size_t)T * 64 * 4);
    float* sinT = (float*)alloc((size_t)T * 64 * 4);
    unsigned short* hb  = (unsigned short*)alloc((size_t)T * HIDDEN * 2);
    unsigned short* wqt = (unsigned short*)alloc((size_t)QKV_N * HIDDEN * 2);
    unsigned short* wot = (unsigned short*)alloc((size_t)HIDDEN * HIDDEN * 2);
    unsigned short* qb  = (unsigned short*)alloc((size_t)T * Q_SIZE * 2);
    unsigned short* kb  = (unsigned short*)alloc((size_t)T * KV_SIZE * 2);
    unsigned short* vb  = (unsigned short*)alloc((size_t)T * KV_SIZE * 2);
    unsigned short* vt  = (unsigned short*)alloc((size_t)T * KV_SIZE * 2);
    unsigned short* ab  = (unsigned short*)alloc((size_t)T * Q_SIZE * 2);
    float* Opart  = (float*)alloc((size_t)1024 * 64 * 128 * 4);   // 33.5 MB
    float* MLpart = (float*)alloc((size_t)1024 * 64 * 2 * 4);

    dim3 tb(32, 8);
    prep_cossin<<<T, 64, 0, stream>>>(positions, cosT, sinT);
    convert_f32_bf16<<<(T * HIDDEN) / 1024, 256, 0, stream>>>(hidden, hb, T * HIDDEN);
    transpose_f32_bf16<<<dim3(QKV_N / 32, HIDDEN / 32), tb, 0, stream>>>(w_qkv, wqt, HIDDEN, QKV_N);
    transpose_f32_bf16<<<dim3(HIDDEN / 32, HIDDEN / 32), tb, 0, stream>>>(w_o, wot, HIDDEN, HIDDEN);
    // fused qkv projection + rope -> qb (scaled), kb, vb
    gemm_qkv<<<dim3(T / 128, QKV_N / 128), 256, 0, stream>>>(hb, wqt, cosT, sinT, qb, kb, vb);
    transpose_bf16<<<dim3(HD / 32, T / 32, NKV), tb, 0, stream>>>(vb, vt, T, HD);
    // fused causal attention, K-split x2 -> partials -> combine -> ab bf16
    flash_attn<<<dim3(1024), 256, 0, stream>>>(qb, kb, vt, Opart, MLpart);
    attn_combine<<<dim3(T / 16, NH), 256, 0, stream>>>(Opart, MLpart, ab);
    // out = attn @ w_o (fp32 out)
    gemm_out<<<dim3(T / 128, HIDDEN / 128), 256, 0, stream>>>(ab, wot, out, Q_SIZE, HIDDEN);
}

// Round 8
// 267.142 us; speedup vs baseline: 1.3615x; 1.0498x over previous
//
#include <hip/hip_runtime.h>
#include <math.h>

#define T 2048
#define HIDDEN 2048
#define NH 16
#define NKV 4
#define HD 128
#define QKV_N 3072   // (16 + 2*4) * 128
#define Q_SIZE 2048  // 16*128
#define KV_SIZE 512  // 4*128

typedef __attribute__((ext_vector_type(8))) short short8;
typedef __attribute__((ext_vector_type(4))) short short4v;
typedef __attribute__((ext_vector_type(4))) float floatx4;

__device__ __forceinline__ unsigned short f2bf(float f) {
    union { float f; unsigned int u; } v; v.f = f;
    unsigned int u = v.u;
    u += 0x7fffu + ((u >> 16) & 1u);   // round-to-nearest-even
    return (unsigned short)(u >> 16);
}

// async global->LDS, 16B per lane; LDS dest = wave-uniform base + lane*16 (HW adds it)
__device__ __forceinline__ void gload_lds16(const unsigned short* g, unsigned short* l) {
    __builtin_amdgcn_global_load_lds((const __attribute__((address_space(1))) unsigned int*)g,
                                     (__attribute__((address_space(3))) unsigned int*)l, 16, 0, 0);
}

// ---------------- fused prep: convert hb + transpose wqt + transpose wot + cos/sin ----------------
// grid ranges: [0,4096) convert, [4096,10240) wqt, [10240,14336) wot, [14336,14848) cossin
__global__ __launch_bounds__(256) void prep_misc(const float* __restrict__ hidden,
                                                 const float* __restrict__ w_qkv,
                                                 const float* __restrict__ w_o,
                                                 const int* __restrict__ positions,
                                                 unsigned short* __restrict__ hb,
                                                 unsigned short* __restrict__ wqt,
                                                 unsigned short* __restrict__ wot,
                                                 float* __restrict__ cosT,
                                                 float* __restrict__ sinT) {
    __shared__ float tile[32][33];
    const int b = blockIdx.x;
    const int tid = threadIdx.x;
    const int tx = tid & 31, ty = tid >> 5;

    if (b < 4096) {
        // fp32 -> bf16 convert of hidden (T*HIDDEN elems)
        int i = (b * 256 + tid) * 4;
        float4 v = *(const float4*)(hidden + i);
        hb[i]     = f2bf(v.x);
        hb[i + 1] = f2bf(v.y);
        hb[i + 2] = f2bf(v.z);
        hb[i + 3] = f2bf(v.w);
    } else if (b < 10240) {
        // transpose w_qkv [HIDDEN][QKV_N] -> wqt [QKV_N][HIDDEN]
        int idx = b - 4096;
        int c0 = (idx % 96) * 32, r0 = (idx / 96) * 32;
#pragma unroll
        for (int i = 0; i < 4; ++i)
            tile[ty + i * 8][tx] = w_qkv[(long)(r0 + ty + i * 8) * QKV_N + c0 + tx];
        __syncthreads();
#pragma unroll
        for (int i = 0; i < 4; ++i)
            wqt[(long)(c0 + ty + i * 8) * HIDDEN + r0 + tx] = f2bf(tile[tx][ty + i * 8]);
    } else if (b < 14336) {
        // transpose w_o [HIDDEN][HIDDEN] -> wot
        int idx = b - 10240;
        int c0 = (idx % 64) * 32, r0 = (idx / 64) * 32;
#pragma unroll
        for (int i = 0; i < 4; ++i)
            tile[ty + i * 8][tx] = w_o[(long)(r0 + ty + i * 8) * HIDDEN + c0 + tx];
        __syncthreads();
#pragma unroll
        for (int i = 0; i < 4; ++i)
            wot[(long)(c0 + ty + i * 8) * HIDDEN + r0 + tx] = f2bf(tile[tx][ty + i * 8]);
    } else {
        // mrope cos/sin tables (fp32). row(j) = 0 if j>=44 else (2 if odd else 1)
        int idx = b - 14336;
        int t = idx * 4 + (tid >> 6);
        int j = tid & 63;
        int row = (j >= 44) ? 0 : ((j & 1) ? 2 : 1);
        int pos = positions[row * T + t];
        float invf = exp2f((float)j * -0.29580571f);   // log2(500000)/64
        float ang = (float)pos * invf;
        cosT[t * 64 + j] = cosf(ang);
        sinT[t * 64 + j] = sinf(ang);
    }
}

// ---------------- qkv GEMM, double-buffered async, rope fused; writes qb, kb, vt ----------------
__global__ __launch_bounds__(256) void gemm_qkv(const unsigned short* __restrict__ A,
                                                const unsigned short* __restrict__ B,
                                                const float* __restrict__ cosT,
                                                const float* __restrict__ sinT,
                                                unsigned short* __restrict__ qb,
                                                unsigned short* __restrict__ kb,
                                                unsigned short* __restrict__ vt) {
    __shared__ __align__(16) unsigned short As[2][128 * 32];
    __shared__ __align__(16) unsigned short Bs[2][128 * 32];
    const int K = HIDDEN;
    const int tid = threadIdx.x;
    const int wv = tid >> 6;
    const int wr = wv >> 1, wc = wv & 1;
    const int lane = tid & 63;
    const int m = lane & 15, qd = lane >> 4;
    const unsigned short* Ab = A + (long)(blockIdx.x * 128) * K;
    const unsigned short* Bb = B + (long)(blockIdx.y * 128) * K;
    const int srow = lane >> 2;
    const int scol = (lane & 3) * 8;

    floatx4 acc[4][4];
#pragma unroll
    for (int i = 0; i < 4; ++i)
#pragma unroll
        for (int j = 0; j < 4; ++j) acc[i][j] = (floatx4){0.f, 0.f, 0.f, 0.f};

#define QKV_STAGE(buf, k0)                                                              \
    do {                                                                                \
        gload_lds16(Ab + (long)(wv * 16 + srow) * K + (k0) + scol,      &As[buf][wv * 512]);        \
        gload_lds16(Ab + (long)(64 + wv * 16 + srow) * K + (k0) + scol, &As[buf][2048 + wv * 512]); \
        gload_lds16(Bb + (long)(wv * 16 + srow) * K + (k0) + scol,      &Bs[buf][wv * 512]);        \
        gload_lds16(Bb + (long)(64 + wv * 16 + srow) * K + (k0) + scol, &Bs[buf][2048 + wv * 512]); \
    } while (0)

    QKV_STAGE(0, 0);
    int cur = 0;
    for (int k0 = 0; k0 < K; k0 += 32) {
        __syncthreads();
        if (k0 + 32 < K) QKV_STAGE(cur ^ 1, k0 + 32);
        short8 a[4], b[4];
#pragma unroll
        for (int i = 0; i < 4; ++i) a[i] = *(const short8*)&As[cur][(wr * 64 + i * 16 + m) * 32 + qd * 8];
#pragma unroll
        for (int j = 0; j < 4; ++j) b[j] = *(const short8*)&Bs[cur][(wc * 64 + j * 16 + m) * 32 + qd * 8];
#pragma unroll
        for (int i = 0; i < 4; ++i)
#pragma unroll
            for (int j = 0; j < 4; ++j)
                acc[i][j] = __builtin_amdgcn_mfma_f32_16x16x32_bf16(a[i], b[j], acc[i][j], 0, 0, 0);
        cur ^= 1;
    }
#undef QKV_STAGE

    const int by = blockIdx.y;
    if (by < 20) {
        // rope path (q: by<16, k: 16..19); pairs are adjacent cols -> shfl_xor(val,1)
        const float sgn = (m & 1) ? 1.f : -1.f;
        const float qscale = 0.08838834764831845f;   // 1/sqrt(128)
#pragma unroll
        for (int i = 0; i < 4; ++i) {
#pragma unroll
            for (int r = 0; r < 4; ++r) {
                const int t = blockIdx.x * 128 + wr * 64 + i * 16 + qd * 4 + r;
                const float* ct = cosT + t * 64;
                const float* st = sinT + t * 64;
#pragma unroll
                for (int j = 0; j < 4; ++j) {
                    const int cq = wc * 64 + j * 16 + m;
                    const int j2 = cq >> 1;
                    float val = acc[i][j][r];
                    float prt = __shfl_xor(val, 1);
                    float o = val * ct[j2] + sgn * prt * st[j2];
                    const int col = by * 128 + cq;
                    if (by < 16) qb[(long)t * Q_SIZE + col] = f2bf(o * qscale);
                    else         kb[(long)t * KV_SIZE + (col - 2048)] = f2bf(o);
                }
            }
        }
    } else {
        // v path: write V^T directly: vt[g][d][t], consecutive r = consecutive t -> short4 stores
        const int g = by - 20;
#pragma unroll
        for (int i = 0; i < 4; ++i)
#pragma unroll
            for (int j = 0; j < 4; ++j) {
                const int d = wc * 64 + j * 16 + m;
                const int t0 = blockIdx.x * 128 + wr * 64 + i * 16 + qd * 4;
                unsigned short o4[4];
#pragma unroll
                for (int r = 0; r < 4; ++r) o4[r] = f2bf(acc[i][j][r]);
                *(short4v*)&vt[((long)g * HD + d) * T + t0] = *(short4v*)o4;
            }
    }
}

// ---------------- out GEMM, double-buffered async: C(fp32) = A * B^T ----------------
__global__ __launch_bounds__(256) void gemm_out(const unsigned short* __restrict__ A,
                                                const unsigned short* __restrict__ B,
                                                float* __restrict__ C,
                                                int K, int ldc) {
    __shared__ __align__(16) unsigned short As[2][128 * 32];
    __shared__ __align__(16) unsigned short Bs[2][128 * 32];
    const int tid = threadIdx.x;
    const int wv = tid >> 6;
    const int wr = wv >> 1, wc = wv & 1;
    const int lane = tid & 63;
    const int m = lane & 15, qd = lane >> 4;
    const unsigned short* Ab = A + (long)(blockIdx.x * 128) * K;
    const unsigned short* Bb = B + (long)(blockIdx.y * 128) * K;
    const int srow = lane >> 2;
    const int scol = (lane & 3) * 8;

    floatx4 acc[4][4];
#pragma unroll
    for (int i = 0; i < 4; ++i)
#pragma unroll
        for (int j = 0; j < 4; ++j) acc[i][j] = (floatx4){0.f, 0.f, 0.f, 0.f};

#define OUT_STAGE(buf, k0)                                                              \
    do {                                                                                \
        gload_lds16(Ab + (long)(wv * 16 + srow) * K + (k0) + scol,      &As[buf][wv * 512]);        \
        gload_lds16(Ab + (long)(64 + wv * 16 + srow) * K + (k0) + scol, &As[buf][2048 + wv * 512]); \
        gload_lds16(Bb + (long)(wv * 16 + srow) * K + (k0) + scol,      &Bs[buf][wv * 512]);        \
        gload_lds16(Bb + (long)(64 + wv * 16 + srow) * K + (k0) + scol, &Bs[buf][2048 + wv * 512]); \
    } while (0)

    OUT_STAGE(0, 0);
    int cur = 0;
    for (int k0 = 0; k0 < K; k0 += 32) {
        __syncthreads();
        if (k0 + 32 < K) OUT_STAGE(cur ^ 1, k0 + 32);
        short8 a[4], b[4];
#pragma unroll
        for (int i = 0; i < 4; ++i) a[i] = *(const short8*)&As[cur][(wr * 64 + i * 16 + m) * 32 + qd * 8];
#pragma unroll
        for (int j = 0; j < 4; ++j) b[j] = *(const short8*)&Bs[cur][(wc * 64 + j * 16 + m) * 32 + qd * 8];
#pragma unroll
        for (int i = 0; i < 4; ++i)
#pragma unroll
            for (int j = 0; j < 4; ++j)
                acc[i][j] = __builtin_amdgcn_mfma_f32_16x16x32_bf16(a[i], b[j], acc[i][j], 0, 0, 0);
        cur ^= 1;
    }
#undef OUT_STAGE

#pragma unroll
    for (int i = 0; i < 4; ++i)
#pragma unroll
        for (int j = 0; j < 4; ++j)
#pragma unroll
            for (int r = 0; r < 4; ++r)
                C[(long)(blockIdx.x * 128 + wr * 64 + i * 16 + qd * 4 + r) * ldc +
                  blockIdx.y * 128 + wc * 64 + j * 16 + m] = acc[i][j][r];
}

// ---------------- flash attention v6: 128 Q-rows/block, paired units, K dbuf + V single ----------
// grid(512): bx = h*32 + c32. Block processes 2 units (qt,half) paired so work = 17 tile-iters.
// Each wave: 2 q-sets of 16 rows (q = q0 + s*64 + wv*16 + m) sharing K/V LDS fragments.
// K double-buffered (prefetch after top barrier); V single-buffered (load after top barrier,
// consumed after mid barrier). P per-wave LDS round-trip. No register prefetch state.
__global__ __launch_bounds__(256, 2) void flash_attn(const unsigned short* __restrict__ qb,
                                                     const unsigned short* __restrict__ kb,
                                                     const unsigned short* __restrict__ vt,
                                                     float* __restrict__ Opart,
                                                     float* __restrict__ MLpart) {
    __shared__ __align__(16) unsigned short Kbuf[2][64 * 128];   // 32 KB
    __shared__ __align__(16) unsigned short Vbuf[128 * 64];      // 16 KB
    __shared__ __align__(16) unsigned short Pls[4][32 * 72];     // 18.4 KB

    const int tid = threadIdx.x;
    const int wv = tid >> 6;
    const int lane = tid & 63;
    const int m = lane & 15;
    const int qd = lane >> 4;

    const int h = blockIdx.x >> 5;
    const int c32 = blockIdx.x & 31;
    const int g = h >> 2;
    unsigned short* myP = Pls[wv];

    for (int seg = 0; seg < 2; ++seg) {
        int qt, half;
        if (c32 < 16) { qt = (seg == 0) ? c32 : 15 - c32; half = seg; }
        else { int cc = c32 - 16; qt = (seg == 0) ? cc : 15 - cc; half = 1 - seg; }
        const int n0 = qt + 1;
        const int jt0 = half ? n0 : 0;
        const int jt1 = half ? 2 * qt + 2 : n0;
        const int q0 = qt * 128;

        short8 aq[2][4];
#pragma unroll
        for (int s = 0; s < 2; ++s)
#pragma unroll
            for (int kk = 0; kk < 4; ++kk)
                aq[s][kk] = *(const short8*)(qb + (long)(q0 + s * 64 + wv * 16 + m) * Q_SIZE +
                                             h * HD + kk * 32 + qd * 8);

        floatx4 acc_o[2][8];
#pragma unroll
        for (int s = 0; s < 2; ++s)
#pragma unroll
            for (int nb = 0; nb < 8; ++nb) acc_o[s][nb] = (floatx4){0.f, 0.f, 0.f, 0.f};
        float mrow[2] = {-1e30f, -1e30f};
        float lrow[2] = {0.f, 0.f};

        // stage first K tile (XOR chunk swizzle c^(r&15))
#pragma unroll
        for (int i = 0; i < 4; ++i) {
            int s_ = i * 256 + tid;
            int r = s_ >> 4, c = (s_ & 15) ^ (r & 15);
            gload_lds16(kb + (long)(jt0 * 64 + r) * KV_SIZE + g * HD + c * 8,
                        &Kbuf[0][i * 2048 + wv * 512]);
        }
        int cur = 0;
        for (int jt = jt0; jt < jt1; ++jt) {
            __syncthreads();   // K[cur] landed; all prior LDS readers done

            if (jt + 1 < jt1) {   // K prefetch -> other buffer (full iter to land)
#pragma unroll
                for (int i = 0; i < 4; ++i) {
                    int s_ = i * 256 + tid;
                    int r = s_ >> 4, c = (s_ & 15) ^ (r & 15);
                    gload_lds16(kb + (long)((jt + 1) * 64 + r) * KV_SIZE + g * HD + c * 8,
                                &Kbuf[cur ^ 1][i * 2048 + wv * 512]);
                }
            }
            // V for CURRENT tile (single buffer; consumed after mid barrier)
#pragma unroll
            for (int i = 0; i < 4; ++i) {
                int s_ = i * 256 + tid;
                int r = s_ >> 3, c = (s_ & 7) ^ (r & 7);
                gload_lds16(vt + ((long)g * HD + r) * T + jt * 64 + c * 8,
                            &Vbuf[i * 2048 + wv * 512]);
            }

            // S^T = K Q^T for both q-sets, sharing K fragment loads
            floatx4 acc_s[2][4];
#pragma unroll
            for (int s = 0; s < 2; ++s)
#pragma unroll
                for (int c = 0; c < 4; ++c) acc_s[s][c] = (floatx4){0.f, 0.f, 0.f, 0.f};
#pragma unroll
            for (int kk = 0; kk < 4; ++kk) {
#pragma unroll
                for (int c = 0; c < 4; ++c) {
                    short8 ak = *(const short8*)&Kbuf[cur][(c * 16 + m) * 128 +
                                                           (((4 * kk + qd) ^ m) * 8)];
                    acc_s[0][c] = __builtin_amdgcn_mfma_f32_16x16x32_bf16(ak, aq[0][kk], acc_s[0][c], 0, 0, 0);
                    acc_s[1][c] = __builtin_amdgcn_mfma_f32_16x16x32_bf16(ak, aq[1][kk], acc_s[1][c], 0, 0, 0);
                }
            }

            // per-set online softmax + P write
#pragma unroll
            for (int s = 0; s < 2; ++s) {
                const int dg = 2 * qt + s;
                if (jt >= dg) {
                    const bool full = (jt > dg);
#pragma unroll
                    for (int c = 0; c < 4; ++c)
#pragma unroll
                        for (int r = 0; r < 4; ++r)
                            if (full || (c * 16 + qd * 4 + r > wv * 16 + m)) acc_s[s][c][r] = -1e30f;
                }
                float mx = acc_s[s][0][0];
#pragma unroll
                for (int c = 0; c < 4; ++c)
#pragma unroll
                    for (int r = 0; r < 4; ++r) mx = fmaxf(mx, acc_s[s][c][r]);
                mx = fmaxf(mx, __shfl_xor(mx, 16));
                mx = fmaxf(mx, __shfl_xor(mx, 32));
                float mnew = fmaxf(mrow[s], mx);
                float alpha = __expf(mrow[s] - mnew);
                mrow[s] = mnew;

                float pv[4][4];
                float lsum = 0.f;
#pragma unroll
                for (int c = 0; c < 4; ++c)
#pragma unroll
                    for (int r = 0; r < 4; ++r) {
                        pv[c][r] = __expf(acc_s[s][c][r] - mnew);
                        lsum += pv[c][r];
                    }
                lsum += __shfl_xor(lsum, 16);
                lsum += __shfl_xor(lsum, 32);
                lrow[s] = lrow[s] * alpha + lsum;
#pragma unroll
                for (int nb = 0; nb < 8; ++nb)
#pragma unroll
                    for (int r = 0; r < 4; ++r) acc_o[s][nb][r] *= alpha;
#pragma unroll
                for (int c = 0; c < 4; ++c) {
                    short4v pk = {(short)f2bf(pv[c][0]), (short)f2bf(pv[c][1]),
                                  (short)f2bf(pv[c][2]), (short)f2bf(pv[c][3])};
                    *(short4v*)&myP[(s * 16 + m) * 72 + c * 16 + qd * 4] = pk;
                }
            }

            __syncthreads();   // V landed (and block-wide sync)

            // PV for both sets, sharing V fragment loads
#pragma unroll
            for (int kk = 0; kk < 2; ++kk) {
                short8 pa0 = *(const short8*)&myP[m * 72 + kk * 32 + qd * 8];
                short8 pa1 = *(const short8*)&myP[(16 + m) * 72 + kk * 32 + qd * 8];
#pragma unroll
                for (int nb = 0; nb < 8; ++nb) {
                    short8 av = *(const short8*)&Vbuf[(nb * 16 + m) * 64 +
                                                      (((4 * kk + qd) ^ (m & 7)) * 8)];
                    acc_o[0][nb] = __builtin_amdgcn_mfma_f32_16x16x32_bf16(av, pa0, acc_o[0][nb], 0, 0, 0);
                    acc_o[1][nb] = __builtin_amdgcn_mfma_f32_16x16x32_bf16(av, pa1, acc_o[1][nb], 0, 0, 0);
                }
            }
            cur ^= 1;
        }

        // store partials for this unit
        const int unit = (h * 16 + qt) * 2 + half;
#pragma unroll
        for (int s = 0; s < 2; ++s) {
            const long rb = (long)unit * 128 + s * 64 + wv * 16 + m;
#pragma unroll
            for (int nb = 0; nb < 8; ++nb)
                *(floatx4*)&Opart[rb * 128 + nb * 16 + qd * 4] = acc_o[s][nb];
            if (qd == 0) {
                MLpart[rb * 2]     = mrow[s];
                MLpart[rb * 2 + 1] = lrow[s];
            }
        }
    }
}

// ---------------- combine K-split partials -> ab bf16 [t][h*128+d] ----------------
__global__ __launch_bounds__(256) void attn_combine(const float* __restrict__ Opart,
                                                    const float* __restrict__ MLpart,
                                                    unsigned short* __restrict__ ab) {
    const int tid = threadIdx.x;
    const int q = blockIdx.x * 16 + (tid >> 4);
    const int h = blockIdx.y;
    const int d0 = (tid & 15) * 8;
    const int qt = q >> 7, lr = q & 127;
    const long r0 = ((long)(h * 16 + qt) * 2) * 128 + lr;
    const long r1 = r0 + 128;
    float m0 = MLpart[r0 * 2], l0 = MLpart[r0 * 2 + 1];
    float m1 = MLpart[r1 * 2], l1 = MLpart[r1 * 2 + 1];
    float M = fmaxf(m0, m1);
    float a0 = __expf(m0 - M), a1 = __expf(m1 - M);
    float inv = 1.f / (l0 * a0 + l1 * a1);
    const float* O0 = Opart + r0 * 128 + d0;
    const float* O1 = Opart + r1 * 128 + d0;
    unsigned short outv[8];
#pragma unroll
    for (int j = 0; j < 8; j += 4) {
        float4 x0 = *(const float4*)(O0 + j);
        float4 x1 = *(const float4*)(O1 + j);
        outv[j]     = f2bf((x0.x * a0 + x1.x * a1) * inv);
        outv[j + 1] = f2bf((x0.y * a0 + x1.y * a1) * inv);
        outv[j + 2] = f2bf((x0.z * a0 + x1.z * a1) * inv);
        outv[j + 3] = f2bf((x0.w * a0 + x1.w * a1) * inv);
    }
    *(short8*)&ab[(long)q * Q_SIZE + h * HD + d0] = *(short8*)outv;
}

extern "C" void kernel_launch(void* const* d_in, const int* in_sizes, int n_in,
                              void* d_out, int out_size, void* d_ws, size_t ws_size,
                              hipStream_t stream) {
    const int* positions = (const int*)d_in[0];
    const float* hidden  = (const float*)d_in[1];
    const float* w_qkv   = (const float*)d_in[2];
    const float* w_o     = (const float*)d_in[3];
    float* out = (float*)d_out;

    char* p = (char*)d_ws;
    auto alloc = [&](size_t bytes) { char* r = p; p += (bytes + 255) & ~(size_t)255; return r; };
    float* cosT = (float*)alloc((size_t)T * 64 * 4);
    float* sinT = (float*)alloc((size_t)T * 64 * 4);
    unsigned short* hb  = (unsigned short*)alloc((size_t)T * HIDDEN * 2);
    unsigned short* wqt = (unsigned short*)alloc((size_t)QKV_N * HIDDEN * 2);
    unsigned short* wot = (unsigned short*)alloc((size_t)HIDDEN * HIDDEN * 2);
    unsigned short* qb  = (unsigned short*)alloc((size_t)T * Q_SIZE * 2);
    unsigned short* kb  = (unsigned short*)alloc((size_t)T * KV_SIZE * 2);
    unsigned short* vt  = (unsigned short*)alloc((size_t)T * KV_SIZE * 2);
    unsigned short* ab  = (unsigned short*)alloc((size_t)T * Q_SIZE * 2);
    float* Opart  = (float*)alloc((size_t)512 * 128 * 128 * 4);   // 33.5 MB
    float* MLpart = (float*)alloc((size_t)512 * 128 * 2 * 4);

    // 1) fused prep (convert + 2 transposes + cos/sin tables)
    prep_misc<<<dim3(14848), 256, 0, stream>>>(hidden, w_qkv, w_o, positions,
                                               hb, wqt, wot, cosT, sinT);
    // 2) fused qkv projection + rope -> qb (scaled), kb, vt (V^T direct)
    gemm_qkv<<<dim3(T / 128, QKV_N / 128), 256, 0, stream>>>(hb, wqt, cosT, sinT, qb, kb, vt);
    // 3) fused causal attention (128-row blocks, paired units, K-split x2)
    flash_attn<<<dim3(512), 256, 0, stream>>>(qb, kb, vt, Opart, MLpart);
    // 4) combine partials
    attn_combine<<<dim3(T / 16, NH), 256, 0, stream>>>(Opart, MLpart, ab);
    // 5) out = attn @ w_o (fp32 out)
    gemm_out<<<dim3(T / 128, HIDDEN / 128), 256, 0, stream>>>(ab, wot, out, Q_SIZE, HIDDEN);
}

// Round 9
// 253.897 us; speedup vs baseline: 1.4325x; 1.0522x over previous
//
#include <hip/hip_runtime.h>
#include <math.h>

#define T 2048
#define HIDDEN 2048
#define NH 16
#define NKV 4
#define HD 128
#define QKV_N 3072   // (16 + 2*4) * 128
#define Q_SIZE 2048  // 16*128
#define KV_SIZE 512  // 4*128

typedef __attribute__((ext_vector_type(8))) short short8;
typedef __attribute__((ext_vector_type(4))) short short4v;
typedef __attribute__((ext_vector_type(4))) float floatx4;

__device__ __forceinline__ unsigned short f2bf(float f) {
    union { float f; unsigned int u; } v; v.f = f;
    unsigned int u = v.u;
    u += 0x7fffu + ((u >> 16) & 1u);   // round-to-nearest-even
    return (unsigned short)(u >> 16);
}

// async global->LDS, 16B per lane; LDS dest = wave-uniform base + lane*16 (HW adds it)
__device__ __forceinline__ void gload_lds16(const unsigned short* g, unsigned short* l) {
    __builtin_amdgcn_global_load_lds((const __attribute__((address_space(1))) unsigned int*)g,
                                     (__attribute__((address_space(3))) unsigned int*)l, 16, 0, 0);
}

// ---------------- fused prep: convert hb + transpose wqt + transpose wot + cos/sin ----------------
// grid ranges: [0,4096) convert, [4096,10240) wqt, [10240,14336) wot, [14336,14848) cossin
__global__ __launch_bounds__(256) void prep_misc(const float* __restrict__ hidden,
                                                 const float* __restrict__ w_qkv,
                                                 const float* __restrict__ w_o,
                                                 const int* __restrict__ positions,
                                                 unsigned short* __restrict__ hb,
                                                 unsigned short* __restrict__ wqt,
                                                 unsigned short* __restrict__ wot,
                                                 float* __restrict__ cosT,
                                                 float* __restrict__ sinT) {
    __shared__ float tile[32][33];
    const int b = blockIdx.x;
    const int tid = threadIdx.x;
    const int tx = tid & 31, ty = tid >> 5;

    if (b < 4096) {
        int i = (b * 256 + tid) * 4;
        float4 v = *(const float4*)(hidden + i);
        hb[i]     = f2bf(v.x);
        hb[i + 1] = f2bf(v.y);
        hb[i + 2] = f2bf(v.z);
        hb[i + 3] = f2bf(v.w);
    } else if (b < 10240) {
        int idx = b - 4096;
        int c0 = (idx % 96) * 32, r0 = (idx / 96) * 32;
#pragma unroll
        for (int i = 0; i < 4; ++i)
            tile[ty + i * 8][tx] = w_qkv[(long)(r0 + ty + i * 8) * QKV_N + c0 + tx];
        __syncthreads();
#pragma unroll
        for (int i = 0; i < 4; ++i)
            wqt[(long)(c0 + ty + i * 8) * HIDDEN + r0 + tx] = f2bf(tile[tx][ty + i * 8]);
    } else if (b < 14336) {
        int idx = b - 10240;
        int c0 = (idx % 64) * 32, r0 = (idx / 64) * 32;
#pragma unroll
        for (int i = 0; i < 4; ++i)
            tile[ty + i * 8][tx] = w_o[(long)(r0 + ty + i * 8) * HIDDEN + c0 + tx];
        __syncthreads();
#pragma unroll
        for (int i = 0; i < 4; ++i)
            wot[(long)(c0 + ty + i * 8) * HIDDEN + r0 + tx] = f2bf(tile[tx][ty + i * 8]);
    } else {
        int idx = b - 14336;
        int t = idx * 4 + (tid >> 6);
        int j = tid & 63;
        int row = (j >= 44) ? 0 : ((j & 1) ? 2 : 1);
        int pos = positions[row * T + t];
        float invf = exp2f((float)j * -0.29580571f);   // log2(500000)/64
        float ang = (float)pos * invf;
        cosT[t * 64 + j] = cosf(ang);
        sinT[t * 64 + j] = sinf(ang);
    }
}

// ---------------- qkv GEMM, double-buffered async, rope fused; writes qb, kb, vt ----------------
__global__ __launch_bounds__(256) void gemm_qkv(const unsigned short* __restrict__ A,
                                                const unsigned short* __restrict__ B,
                                                const float* __restrict__ cosT,
                                                const float* __restrict__ sinT,
                                                unsigned short* __restrict__ qb,
                                                unsigned short* __restrict__ kb,
                                                unsigned short* __restrict__ vt) {
    __shared__ __align__(16) unsigned short As[2][128 * 32];
    __shared__ __align__(16) unsigned short Bs[2][128 * 32];
    const int K = HIDDEN;
    const int tid = threadIdx.x;
    const int wv = tid >> 6;
    const int wr = wv >> 1, wc = wv & 1;
    const int lane = tid & 63;
    const int m = lane & 15, qd = lane >> 4;
    const unsigned short* Ab = A + (long)(blockIdx.x * 128) * K;
    const unsigned short* Bb = B + (long)(blockIdx.y * 128) * K;
    const int srow = lane >> 2;
    const int scol = (lane & 3) * 8;

    floatx4 acc[4][4];
#pragma unroll
    for (int i = 0; i < 4; ++i)
#pragma unroll
        for (int j = 0; j < 4; ++j) acc[i][j] = (floatx4){0.f, 0.f, 0.f, 0.f};

#define QKV_STAGE(buf, k0)                                                              \
    do {                                                                                \
        gload_lds16(Ab + (long)(wv * 16 + srow) * K + (k0) + scol,      &As[buf][wv * 512]);        \
        gload_lds16(Ab + (long)(64 + wv * 16 + srow) * K + (k0) + scol, &As[buf][2048 + wv * 512]); \
        gload_lds16(Bb + (long)(wv * 16 + srow) * K + (k0) + scol,      &Bs[buf][wv * 512]);        \
        gload_lds16(Bb + (long)(64 + wv * 16 + srow) * K + (k0) + scol, &Bs[buf][2048 + wv * 512]); \
    } while (0)

    QKV_STAGE(0, 0);
    int cur = 0;
    for (int k0 = 0; k0 < K; k0 += 32) {
        __syncthreads();
        if (k0 + 32 < K) QKV_STAGE(cur ^ 1, k0 + 32);
        short8 a[4], b[4];
#pragma unroll
        for (int i = 0; i < 4; ++i) a[i] = *(const short8*)&As[cur][(wr * 64 + i * 16 + m) * 32 + qd * 8];
#pragma unroll
        for (int j = 0; j < 4; ++j) b[j] = *(const short8*)&Bs[cur][(wc * 64 + j * 16 + m) * 32 + qd * 8];
#pragma unroll
        for (int i = 0; i < 4; ++i)
#pragma unroll
            for (int j = 0; j < 4; ++j)
                acc[i][j] = __builtin_amdgcn_mfma_f32_16x16x32_bf16(a[i], b[j], acc[i][j], 0, 0, 0);
        cur ^= 1;
    }
#undef QKV_STAGE

    const int by = blockIdx.y;
    if (by < 20) {
        const float sgn = (m & 1) ? 1.f : -1.f;
        const float qscale = 0.08838834764831845f;   // 1/sqrt(128)
#pragma unroll
        for (int i = 0; i < 4; ++i) {
#pragma unroll
            for (int r = 0; r < 4; ++r) {
                const int t = blockIdx.x * 128 + wr * 64 + i * 16 + qd * 4 + r;
                const float* ct = cosT + t * 64;
                const float* st = sinT + t * 64;
#pragma unroll
                for (int j = 0; j < 4; ++j) {
                    const int cq = wc * 64 + j * 16 + m;
                    const int j2 = cq >> 1;
                    float val = acc[i][j][r];
                    float prt = __shfl_xor(val, 1);
                    float o = val * ct[j2] + sgn * prt * st[j2];
                    const int col = by * 128 + cq;
                    if (by < 16) qb[(long)t * Q_SIZE + col] = f2bf(o * qscale);
                    else         kb[(long)t * KV_SIZE + (col - 2048)] = f2bf(o);
                }
            }
        }
    } else {
        const int g = by - 20;
#pragma unroll
        for (int i = 0; i < 4; ++i)
#pragma unroll
            for (int j = 0; j < 4; ++j) {
                const int d = wc * 64 + j * 16 + m;
                const int t0 = blockIdx.x * 128 + wr * 64 + i * 16 + qd * 4;
                unsigned short o4[4];
#pragma unroll
                for (int r = 0; r < 4; ++r) o4[r] = f2bf(acc[i][j][r]);
                *(short4v*)&vt[((long)g * HD + d) * T + t0] = *(short4v*)o4;
            }
    }
}

// ---------------- out GEMM, double-buffered async: C(fp32) = A * B^T ----------------
__global__ __launch_bounds__(256) void gemm_out(const unsigned short* __restrict__ A,
                                                const unsigned short* __restrict__ B,
                                                float* __restrict__ C,
                                                int K, int ldc) {
    __shared__ __align__(16) unsigned short As[2][128 * 32];
    __shared__ __align__(16) unsigned short Bs[2][128 * 32];
    const int tid = threadIdx.x;
    const int wv = tid >> 6;
    const int wr = wv >> 1, wc = wv & 1;
    const int lane = tid & 63;
    const int m = lane & 15, qd = lane >> 4;
    const unsigned short* Ab = A + (long)(blockIdx.x * 128) * K;
    const unsigned short* Bb = B + (long)(blockIdx.y * 128) * K;
    const int srow = lane >> 2;
    const int scol = (lane & 3) * 8;

    floatx4 acc[4][4];
#pragma unroll
    for (int i = 0; i < 4; ++i)
#pragma unroll
        for (int j = 0; j < 4; ++j) acc[i][j] = (floatx4){0.f, 0.f, 0.f, 0.f};

#define OUT_STAGE(buf, k0)                                                              \
    do {                                                                                \
        gload_lds16(Ab + (long)(wv * 16 + srow) * K + (k0) + scol,      &As[buf][wv * 512]);        \
        gload_lds16(Ab + (long)(64 + wv * 16 + srow) * K + (k0) + scol, &As[buf][2048 + wv * 512]); \
        gload_lds16(Bb + (long)(wv * 16 + srow) * K + (k0) + scol,      &Bs[buf][wv * 512]);        \
        gload_lds16(Bb + (long)(64 + wv * 16 + srow) * K + (k0) + scol, &Bs[buf][2048 + wv * 512]); \
    } while (0)

    OUT_STAGE(0, 0);
    int cur = 0;
    for (int k0 = 0; k0 < K; k0 += 32) {
        __syncthreads();
        if (k0 + 32 < K) OUT_STAGE(cur ^ 1, k0 + 32);
        short8 a[4], b[4];
#pragma unroll
        for (int i = 0; i < 4; ++i) a[i] = *(const short8*)&As[cur][(wr * 64 + i * 16 + m) * 32 + qd * 8];
#pragma unroll
        for (int j = 0; j < 4; ++j) b[j] = *(const short8*)&Bs[cur][(wc * 64 + j * 16 + m) * 32 + qd * 8];
#pragma unroll
        for (int i = 0; i < 4; ++i)
#pragma unroll
            for (int j = 0; j < 4; ++j)
                acc[i][j] = __builtin_amdgcn_mfma_f32_16x16x32_bf16(a[i], b[j], acc[i][j], 0, 0, 0);
        cur ^= 1;
    }
#undef OUT_STAGE

#pragma unroll
    for (int i = 0; i < 4; ++i)
#pragma unroll
        for (int j = 0; j < 4; ++j)
#pragma unroll
            for (int r = 0; r < 4; ++r)
                C[(long)(blockIdx.x * 128 + wr * 64 + i * 16 + qd * 4 + r) * ldc +
                  blockIdx.y * 128 + wc * 64 + j * 16 + m] = acc[i][j][r];
}

// ---------------- flash attention v7: v6 deduplicated ----------------
// grid(256): bx = h*16 + c16. Block runs seg0=(qt=c16,half=0), seg1=(qt=15-c16,half=1):
// covers each (h,qt,half) unit exactly once, 17 tile-iters/block, all blocks co-resident.
// (R8's 512-block pairing double-covered every unit -> 2x flash work, 2x Opart writes.)
__global__ __launch_bounds__(256, 2) void flash_attn(const unsigned short* __restrict__ qb,
                                                     const unsigned short* __restrict__ kb,
                                                     const unsigned short* __restrict__ vt,
                                                     float* __restrict__ Opart,
                                                     float* __restrict__ MLpart) {
    __shared__ __align__(16) unsigned short Kbuf[2][64 * 128];   // 32 KB
    __shared__ __align__(16) unsigned short Vbuf[128 * 64];      // 16 KB
    __shared__ __align__(16) unsigned short Pls[4][32 * 72];     // 18.4 KB

    const int tid = threadIdx.x;
    const int wv = tid >> 6;
    const int lane = tid & 63;
    const int m = lane & 15;
    const int qd = lane >> 4;

    const int h = blockIdx.x >> 4;
    const int c16 = blockIdx.x & 15;
    const int g = h >> 2;
    unsigned short* myP = Pls[wv];

    for (int seg = 0; seg < 2; ++seg) {
        const int qt = seg ? (15 - c16) : c16;
        const int half = seg;
        const int n0 = qt + 1;
        const int jt0 = half ? n0 : 0;
        const int jt1 = half ? 2 * qt + 2 : n0;
        const int q0 = qt * 128;

        short8 aq[2][4];
#pragma unroll
        for (int s = 0; s < 2; ++s)
#pragma unroll
            for (int kk = 0; kk < 4; ++kk)
                aq[s][kk] = *(const short8*)(qb + (long)(q0 + s * 64 + wv * 16 + m) * Q_SIZE +
                                             h * HD + kk * 32 + qd * 8);

        floatx4 acc_o[2][8];
#pragma unroll
        for (int s = 0; s < 2; ++s)
#pragma unroll
            for (int nb = 0; nb < 8; ++nb) acc_o[s][nb] = (floatx4){0.f, 0.f, 0.f, 0.f};
        float mrow[2] = {-1e30f, -1e30f};
        float lrow[2] = {0.f, 0.f};

        // stage first K tile (XOR chunk swizzle c^(r&15))
#pragma unroll
        for (int i = 0; i < 4; ++i) {
            int s_ = i * 256 + tid;
            int r = s_ >> 4, c = (s_ & 15) ^ (r & 15);
            gload_lds16(kb + (long)(jt0 * 64 + r) * KV_SIZE + g * HD + c * 8,
                        &Kbuf[0][i * 2048 + wv * 512]);
        }
        int cur = 0;
        for (int jt = jt0; jt < jt1; ++jt) {
            __syncthreads();   // K[cur] landed; all prior LDS readers done

            if (jt + 1 < jt1) {   // K prefetch -> other buffer (full iter to land)
#pragma unroll
                for (int i = 0; i < 4; ++i) {
                    int s_ = i * 256 + tid;
                    int r = s_ >> 4, c = (s_ & 15) ^ (r & 15);
                    gload_lds16(kb + (long)((jt + 1) * 64 + r) * KV_SIZE + g * HD + c * 8,
                                &Kbuf[cur ^ 1][i * 2048 + wv * 512]);
                }
            }
            // V for CURRENT tile (single buffer; consumed after mid barrier)
#pragma unroll
            for (int i = 0; i < 4; ++i) {
                int s_ = i * 256 + tid;
                int r = s_ >> 3, c = (s_ & 7) ^ (r & 7);
                gload_lds16(vt + ((long)g * HD + r) * T + jt * 64 + c * 8,
                            &Vbuf[i * 2048 + wv * 512]);
            }

            // S^T = K Q^T for both q-sets, sharing K fragment loads
            floatx4 acc_s[2][4];
#pragma unroll
            for (int s = 0; s < 2; ++s)
#pragma unroll
                for (int c = 0; c < 4; ++c) acc_s[s][c] = (floatx4){0.f, 0.f, 0.f, 0.f};
#pragma unroll
            for (int kk = 0; kk < 4; ++kk) {
#pragma unroll
                for (int c = 0; c < 4; ++c) {
                    short8 ak = *(const short8*)&Kbuf[cur][(c * 16 + m) * 128 +
                                                           (((4 * kk + qd) ^ m) * 8)];
                    acc_s[0][c] = __builtin_amdgcn_mfma_f32_16x16x32_bf16(ak, aq[0][kk], acc_s[0][c], 0, 0, 0);
                    acc_s[1][c] = __builtin_amdgcn_mfma_f32_16x16x32_bf16(ak, aq[1][kk], acc_s[1][c], 0, 0, 0);
                }
            }

            // per-set online softmax + P write
#pragma unroll
            for (int s = 0; s < 2; ++s) {
                const int dg = 2 * qt + s;
                if (jt >= dg) {
                    const bool full = (jt > dg);
#pragma unroll
                    for (int c = 0; c < 4; ++c)
#pragma unroll
                        for (int r = 0; r < 4; ++r)
                            if (full || (c * 16 + qd * 4 + r > wv * 16 + m)) acc_s[s][c][r] = -1e30f;
                }
                float mx = acc_s[s][0][0];
#pragma unroll
                for (int c = 0; c < 4; ++c)
#pragma unroll
                    for (int r = 0; r < 4; ++r) mx = fmaxf(mx, acc_s[s][c][r]);
                mx = fmaxf(mx, __shfl_xor(mx, 16));
                mx = fmaxf(mx, __shfl_xor(mx, 32));
                float mnew = fmaxf(mrow[s], mx);
                float alpha = __expf(mrow[s] - mnew);
                mrow[s] = mnew;

                float pv[4][4];
                float lsum = 0.f;
#pragma unroll
                for (int c = 0; c < 4; ++c)
#pragma unroll
                    for (int r = 0; r < 4; ++r) {
                        pv[c][r] = __expf(acc_s[s][c][r] - mnew);
                        lsum += pv[c][r];
                    }
                lsum += __shfl_xor(lsum, 16);
                lsum += __shfl_xor(lsum, 32);
                lrow[s] = lrow[s] * alpha + lsum;
#pragma unroll
                for (int nb = 0; nb < 8; ++nb)
#pragma unroll
                    for (int r = 0; r < 4; ++r) acc_o[s][nb][r] *= alpha;
#pragma unroll
                for (int c = 0; c < 4; ++c) {
                    short4v pk = {(short)f2bf(pv[c][0]), (short)f2bf(pv[c][1]),
                                  (short)f2bf(pv[c][2]), (short)f2bf(pv[c][3])};
                    *(short4v*)&myP[(s * 16 + m) * 72 + c * 16 + qd * 4] = pk;
                }
            }

            __syncthreads();   // V landed (and block-wide sync)

            // PV for both sets, sharing V fragment loads
#pragma unroll
            for (int kk = 0; kk < 2; ++kk) {
                short8 pa0 = *(const short8*)&myP[m * 72 + kk * 32 + qd * 8];
                short8 pa1 = *(const short8*)&myP[(16 + m) * 72 + kk * 32 + qd * 8];
#pragma unroll
                for (int nb = 0; nb < 8; ++nb) {
                    short8 av = *(const short8*)&Vbuf[(nb * 16 + m) * 64 +
                                                      (((4 * kk + qd) ^ (m & 7)) * 8)];
                    acc_o[0][nb] = __builtin_amdgcn_mfma_f32_16x16x32_bf16(av, pa0, acc_o[0][nb], 0, 0, 0);
                    acc_o[1][nb] = __builtin_amdgcn_mfma_f32_16x16x32_bf16(av, pa1, acc_o[1][nb], 0, 0, 0);
                }
            }
            cur ^= 1;
        }

        // store partials for this unit
        const int unit = (h * 16 + qt) * 2 + half;
#pragma unroll
        for (int s = 0; s < 2; ++s) {
            const long rb = (long)unit * 128 + s * 64 + wv * 16 + m;
#pragma unroll
            for (int nb = 0; nb < 8; ++nb)
                *(floatx4*)&Opart[rb * 128 + nb * 16 + qd * 4] = acc_o[s][nb];
            if (qd == 0) {
                MLpart[rb * 2]     = mrow[s];
                MLpart[rb * 2 + 1] = lrow[s];
            }
        }
    }
}

// ---------------- combine K-split partials -> ab bf16 [t][h*128+d] ----------------
__global__ __launch_bounds__(256) void attn_combine(const float* __restrict__ Opart,
                                                    const float* __restrict__ MLpart,
                                                    unsigned short* __restrict__ ab) {
    const int tid = threadIdx.x;
    const int q = blockIdx.x * 16 + (tid >> 4);
    const int h = blockIdx.y;
    const int d0 = (tid & 15) * 8;
    const int qt = q >> 7, lr = q & 127;
    const long r0 = ((long)(h * 16 + qt) * 2) * 128 + lr;
    const long r1 = r0 + 128;
    float m0 = MLpart[r0 * 2], l0 = MLpart[r0 * 2 + 1];
    float m1 = MLpart[r1 * 2], l1 = MLpart[r1 * 2 + 1];
    float M = fmaxf(m0, m1);
    float a0 = __expf(m0 - M), a1 = __expf(m1 - M);
    float inv = 1.f / (l0 * a0 + l1 * a1);
    const float* O0 = Opart + r0 * 128 + d0;
    const float* O1 = Opart + r1 * 128 + d0;
    unsigned short outv[8];
#pragma unroll
    for (int j = 0; j < 8; j += 4) {
        float4 x0 = *(const float4*)(O0 + j);
        float4 x1 = *(const float4*)(O1 + j);
        outv[j]     = f2bf((x0.x * a0 + x1.x * a1) * inv);
        outv[j + 1] = f2bf((x0.y * a0 + x1.y * a1) * inv);
        outv[j + 2] = f2bf((x0.z * a0 + x1.z * a1) * inv);
        outv[j + 3] = f2bf((x0.w * a0 + x1.w * a1) * inv);
    }
    *(short8*)&ab[(long)q * Q_SIZE + h * HD + d0] = *(short8*)outv;
}

extern "C" void kernel_launch(void* const* d_in, const int* in_sizes, int n_in,
                              void* d_out, int out_size, void* d_ws, size_t ws_size,
                              hipStream_t stream) {
    const int* positions = (const int*)d_in[0];
    const float* hidden  = (const float*)d_in[1];
    const float* w_qkv   = (const float*)d_in[2];
    const float* w_o     = (const float*)d_in[3];
    float* out = (float*)d_out;

    char* p = (char*)d_ws;
    auto alloc = [&](size_t bytes) { char* r = p; p += (bytes + 255) & ~(size_t)255; return r; };
    float* cosT = (float*)alloc((size_t)T * 64 * 4);
    float* sinT = (float*)alloc((size_t)T * 64 * 4);
    unsigned short* hb  = (unsigned short*)alloc((size_t)T * HIDDEN * 2);
    unsigned short* wqt = (unsigned short*)alloc((size_t)QKV_N * HIDDEN * 2);
    unsigned short* wot = (unsigned short*)alloc((size_t)HIDDEN * HIDDEN * 2);
    unsigned short* qb  = (unsigned short*)alloc((size_t)T * Q_SIZE * 2);
    unsigned short* kb  = (unsigned short*)alloc((size_t)T * KV_SIZE * 2);
    unsigned short* vt  = (unsigned short*)alloc((size_t)T * KV_SIZE * 2);
    unsigned short* ab  = (unsigned short*)alloc((size_t)T * Q_SIZE * 2);
    float* Opart  = (float*)alloc((size_t)512 * 128 * 128 * 4);   // 33.5 MB
    float* MLpart = (float*)alloc((size_t)512 * 128 * 2 * 4);

    // 1) fused prep (convert + 2 transposes + cos/sin tables)
    prep_misc<<<dim3(14848), 256, 0, stream>>>(hidden, w_qkv, w_o, positions,
                                               hb, wqt, wot, cosT, sinT);
    // 2) fused qkv projection + rope -> qb (scaled), kb, vt (V^T direct)
    gemm_qkv<<<dim3(T / 128, QKV_N / 128), 256, 0, stream>>>(hb, wqt, cosT, sinT, qb, kb, vt);
    // 3) fused causal attention (128-row blocks, dedup pairing, K-split x2)
    flash_attn<<<dim3(256), 256, 0, stream>>>(qb, kb, vt, Opart, MLpart);
    // 4) combine partials
    attn_combine<<<dim3(T / 16, NH), 256, 0, stream>>>(Opart, MLpart, ab);
    // 5) out = attn @ w_o (fp32 out)
    gemm_out<<<dim3(T / 128, HIDDEN / 128), 256, 0, stream>>>(ab, wot, out, Q_SIZE, HIDDEN);
}

// Round 10
// 239.023 us; speedup vs baseline: 1.5217x; 1.0622x over previous
//
#include <hip/hip_runtime.h>
#include <math.h>

#define T 2048
#define HIDDEN 2048
#define NH 16
#define NKV 4
#define HD 128
#define QKV_N 3072   // (16 + 2*4) * 128
#define Q_SIZE 2048  // 16*128
#define KV_SIZE 512  // 4*128

typedef __attribute__((ext_vector_type(8))) short short8;
typedef __attribute__((ext_vector_type(4))) short short4v;
typedef __attribute__((ext_vector_type(4))) float floatx4;

__device__ __forceinline__ unsigned short f2bf(float f) {
    union { float f; unsigned int u; } v; v.f = f;
    unsigned int u = v.u;
    u += 0x7fffu + ((u >> 16) & 1u);   // round-to-nearest-even
    return (unsigned short)(u >> 16);
}

// async global->LDS, 16B per lane; LDS dest = wave-uniform base + lane*16 (HW adds it)
__device__ __forceinline__ void gload_lds16(const unsigned short* g, unsigned short* l) {
    __builtin_amdgcn_global_load_lds((const __attribute__((address_space(1))) unsigned int*)g,
                                     (__attribute__((address_space(3))) unsigned int*)l, 16, 0, 0);
}

// ---------------- fused prep: convert hb + transpose wqt + transpose wot + cos/sin ----------------
// grid ranges: [0,4096) convert, [4096,10240) wqt, [10240,14336) wot, [14336,14848) cossin
__global__ __launch_bounds__(256) void prep_misc(const float* __restrict__ hidden,
                                                 const float* __restrict__ w_qkv,
                                                 const float* __restrict__ w_o,
                                                 const int* __restrict__ positions,
                                                 unsigned short* __restrict__ hb,
                                                 unsigned short* __restrict__ wqt,
                                                 unsigned short* __restrict__ wot,
                                                 float* __restrict__ cosT,
                                                 float* __restrict__ sinT) {
    __shared__ float tile[32][33];
    const int b = blockIdx.x;
    const int tid = threadIdx.x;
    const int tx = tid & 31, ty = tid >> 5;

    if (b < 4096) {
        int i = (b * 256 + tid) * 4;
        float4 v = *(const float4*)(hidden + i);
        hb[i]     = f2bf(v.x);
        hb[i + 1] = f2bf(v.y);
        hb[i + 2] = f2bf(v.z);
        hb[i + 3] = f2bf(v.w);
    } else if (b < 10240) {
        int idx = b - 4096;
        int c0 = (idx % 96) * 32, r0 = (idx / 96) * 32;
#pragma unroll
        for (int i = 0; i < 4; ++i)
            tile[ty + i * 8][tx] = w_qkv[(long)(r0 + ty + i * 8) * QKV_N + c0 + tx];
        __syncthreads();
#pragma unroll
        for (int i = 0; i < 4; ++i)
            wqt[(long)(c0 + ty + i * 8) * HIDDEN + r0 + tx] = f2bf(tile[tx][ty + i * 8]);
    } else if (b < 14336) {
        int idx = b - 10240;
        int c0 = (idx % 64) * 32, r0 = (idx / 64) * 32;
#pragma unroll
        for (int i = 0; i < 4; ++i)
            tile[ty + i * 8][tx] = w_o[(long)(r0 + ty + i * 8) * HIDDEN + c0 + tx];
        __syncthreads();
#pragma unroll
        for (int i = 0; i < 4; ++i)
            wot[(long)(c0 + ty + i * 8) * HIDDEN + r0 + tx] = f2bf(tile[tx][ty + i * 8]);
    } else {
        int idx = b - 14336;
        int t = idx * 4 + (tid >> 6);
        int j = tid & 63;
        int row = (j >= 44) ? 0 : ((j & 1) ? 2 : 1);
        int pos = positions[row * T + t];
        float invf = exp2f((float)j * -0.29580571f);   // log2(500000)/64
        float ang = (float)pos * invf;
        cosT[t * 64 + j] = cosf(ang);
        sinT[t * 64 + j] = sinf(ang);
    }
}

// ---------------- qkv GEMM: 64x128 tile (3 blocks/CU), dbuf async, rope fused ----------------
// Wave layout: wave wv owns cols wv*32..wv*32+32 (2 col-16 groups), all 64 rows.
// grid (T/64=32, QKV_N/128=24) = 768 blocks.
__global__ __launch_bounds__(256) void gemm_qkv(const unsigned short* __restrict__ A,
                                                const unsigned short* __restrict__ B,
                                                const float* __restrict__ cosT,
                                                const float* __restrict__ sinT,
                                                unsigned short* __restrict__ qb,
                                                unsigned short* __restrict__ kb,
                                                unsigned short* __restrict__ vt) {
    __shared__ __align__(16) unsigned short As[2][64 * 32];    // 2 x 4 KB
    __shared__ __align__(16) unsigned short Bs[2][128 * 32];   // 2 x 8 KB
    const int K = HIDDEN;
    const int tid = threadIdx.x;
    const int wv = tid >> 6;
    const int lane = tid & 63;
    const int m = lane & 15, qd = lane >> 4;
    const unsigned short* Ab = A + (long)(blockIdx.x * 64) * K;
    const unsigned short* Bb = B + (long)(blockIdx.y * 128) * K;
    const int srow = tid >> 2;          // 0..63
    const int scol = (tid & 3) * 8;

    floatx4 acc[4][2];
#pragma unroll
    for (int i = 0; i < 4; ++i)
#pragma unroll
        for (int j = 0; j < 2; ++j) acc[i][j] = (floatx4){0.f, 0.f, 0.f, 0.f};

#define QKV_STAGE(buf, k0)                                                                \
    do {                                                                                  \
        gload_lds16(Ab + (long)srow * K + (k0) + scol,        &As[buf][wv * 512]);        \
        gload_lds16(Bb + (long)srow * K + (k0) + scol,        &Bs[buf][wv * 512]);        \
        gload_lds16(Bb + (long)(64 + srow) * K + (k0) + scol, &Bs[buf][2048 + wv * 512]); \
    } while (0)

    QKV_STAGE(0, 0);
    int cur = 0;
    for (int k0 = 0; k0 < K; k0 += 32) {
        __syncthreads();                       // buf[cur] landed; prev readers of buf[cur^1] done
        if (k0 + 32 < K) QKV_STAGE(cur ^ 1, k0 + 32);
        short8 a[4], b[2];
#pragma unroll
        for (int i = 0; i < 4; ++i) a[i] = *(const short8*)&As[cur][(i * 16 + m) * 32 + qd * 8];
#pragma unroll
        for (int j = 0; j < 2; ++j) b[j] = *(const short8*)&Bs[cur][(wv * 32 + j * 16 + m) * 32 + qd * 8];
#pragma unroll
        for (int i = 0; i < 4; ++i)
#pragma unroll
            for (int j = 0; j < 2; ++j)
                acc[i][j] = __builtin_amdgcn_mfma_f32_16x16x32_bf16(a[i], b[j], acc[i][j], 0, 0, 0);
        cur ^= 1;
    }
#undef QKV_STAGE

    const int by = blockIdx.y;
    if (by < 20) {
        // rope path (q: by<16, k: 16..19); pairs are adjacent cols -> shfl_xor(val,1)
        const float sgn = (m & 1) ? 1.f : -1.f;
        const float qscale = 0.08838834764831845f;   // 1/sqrt(128)
#pragma unroll
        for (int i = 0; i < 4; ++i) {
#pragma unroll
            for (int r = 0; r < 4; ++r) {
                const int t = blockIdx.x * 64 + i * 16 + qd * 4 + r;
                const float* ct = cosT + t * 64;
                const float* st = sinT + t * 64;
#pragma unroll
                for (int j = 0; j < 2; ++j) {
                    const int cq = wv * 32 + j * 16 + m;
                    const int j2 = cq >> 1;
                    float val = acc[i][j][r];
                    float prt = __shfl_xor(val, 1);
                    float o = val * ct[j2] + sgn * prt * st[j2];
                    const int col = by * 128 + cq;
                    if (by < 16) qb[(long)t * Q_SIZE + col] = f2bf(o * qscale);
                    else         kb[(long)t * KV_SIZE + (col - 2048)] = f2bf(o);
                }
            }
        }
    } else {
        // v path: write V^T directly: vt[g][d][t], 4 consecutive t per acc -> short4 stores
        const int g = by - 20;
#pragma unroll
        for (int i = 0; i < 4; ++i)
#pragma unroll
            for (int j = 0; j < 2; ++j) {
                const int d = wv * 32 + j * 16 + m;
                const int t0 = blockIdx.x * 64 + i * 16 + qd * 4;
                unsigned short o4[4];
#pragma unroll
                for (int r = 0; r < 4; ++r) o4[r] = f2bf(acc[i][j][r]);
                *(short4v*)&vt[((long)g * HD + d) * T + t0] = *(short4v*)o4;
            }
    }
}

// ---------------- out GEMM: 64x128 tile (2 blocks/CU), dbuf async: C(fp32) = A * B^T ----------
// grid (T/64=32, HIDDEN/128=16) = 512 blocks.
__global__ __launch_bounds__(256) void gemm_out(const unsigned short* __restrict__ A,
                                                const unsigned short* __restrict__ B,
                                                float* __restrict__ C,
                                                int K, int ldc) {
    __shared__ __align__(16) unsigned short As[2][64 * 32];
    __shared__ __align__(16) unsigned short Bs[2][128 * 32];
    const int tid = threadIdx.x;
    const int wv = tid >> 6;
    const int lane = tid & 63;
    const int m = lane & 15, qd = lane >> 4;
    const unsigned short* Ab = A + (long)(blockIdx.x * 64) * K;
    const unsigned short* Bb = B + (long)(blockIdx.y * 128) * K;
    const int srow = tid >> 2;
    const int scol = (tid & 3) * 8;

    floatx4 acc[4][2];
#pragma unroll
    for (int i = 0; i < 4; ++i)
#pragma unroll
        for (int j = 0; j < 2; ++j) acc[i][j] = (floatx4){0.f, 0.f, 0.f, 0.f};

#define OUT_STAGE(buf, k0)                                                                \
    do {                                                                                  \
        gload_lds16(Ab + (long)srow * K + (k0) + scol,        &As[buf][wv * 512]);        \
        gload_lds16(Bb + (long)srow * K + (k0) + scol,        &Bs[buf][wv * 512]);        \
        gload_lds16(Bb + (long)(64 + srow) * K + (k0) + scol, &Bs[buf][2048 + wv * 512]); \
    } while (0)

    OUT_STAGE(0, 0);
    int cur = 0;
    for (int k0 = 0; k0 < K; k0 += 32) {
        __syncthreads();
        if (k0 + 32 < K) OUT_STAGE(cur ^ 1, k0 + 32);
        short8 a[4], b[2];
#pragma unroll
        for (int i = 0; i < 4; ++i) a[i] = *(const short8*)&As[cur][(i * 16 + m) * 32 + qd * 8];
#pragma unroll
        for (int j = 0; j < 2; ++j) b[j] = *(const short8*)&Bs[cur][(wv * 32 + j * 16 + m) * 32 + qd * 8];
#pragma unroll
        for (int i = 0; i < 4; ++i)
#pragma unroll
            for (int j = 0; j < 2; ++j)
                acc[i][j] = __builtin_amdgcn_mfma_f32_16x16x32_bf16(a[i], b[j], acc[i][j], 0, 0, 0);
        cur ^= 1;
    }
#undef OUT_STAGE

#pragma unroll
    for (int i = 0; i < 4; ++i)
#pragma unroll
        for (int j = 0; j < 2; ++j)
#pragma unroll
            for (int r = 0; r < 4; ++r)
                C[(long)(blockIdx.x * 64 + i * 16 + qd * 4 + r) * ldc +
                  blockIdx.y * 128 + wv * 32 + j * 16 + m] = acc[i][j][r];
}

// ---------------- flash attention v7: dedup pairing (unchanged from R9) ----------------
__global__ __launch_bounds__(256, 2) void flash_attn(const unsigned short* __restrict__ qb,
                                                     const unsigned short* __restrict__ kb,
                                                     const unsigned short* __restrict__ vt,
                                                     float* __restrict__ Opart,
                                                     float* __restrict__ MLpart) {
    __shared__ __align__(16) unsigned short Kbuf[2][64 * 128];   // 32 KB
    __shared__ __align__(16) unsigned short Vbuf[128 * 64];      // 16 KB
    __shared__ __align__(16) unsigned short Pls[4][32 * 72];     // 18.4 KB

    const int tid = threadIdx.x;
    const int wv = tid >> 6;
    const int lane = tid & 63;
    const int m = lane & 15;
    const int qd = lane >> 4;

    const int h = blockIdx.x >> 4;
    const int c16 = blockIdx.x & 15;
    const int g = h >> 2;
    unsigned short* myP = Pls[wv];

    for (int seg = 0; seg < 2; ++seg) {
        const int qt = seg ? (15 - c16) : c16;
        const int half = seg;
        const int n0 = qt + 1;
        const int jt0 = half ? n0 : 0;
        const int jt1 = half ? 2 * qt + 2 : n0;
        const int q0 = qt * 128;

        short8 aq[2][4];
#pragma unroll
        for (int s = 0; s < 2; ++s)
#pragma unroll
            for (int kk = 0; kk < 4; ++kk)
                aq[s][kk] = *(const short8*)(qb + (long)(q0 + s * 64 + wv * 16 + m) * Q_SIZE +
                                             h * HD + kk * 32 + qd * 8);

        floatx4 acc_o[2][8];
#pragma unroll
        for (int s = 0; s < 2; ++s)
#pragma unroll
            for (int nb = 0; nb < 8; ++nb) acc_o[s][nb] = (floatx4){0.f, 0.f, 0.f, 0.f};
        float mrow[2] = {-1e30f, -1e30f};
        float lrow[2] = {0.f, 0.f};

        // stage first K tile (XOR chunk swizzle c^(r&15))
#pragma unroll
        for (int i = 0; i < 4; ++i) {
            int s_ = i * 256 + tid;
            int r = s_ >> 4, c = (s_ & 15) ^ (r & 15);
            gload_lds16(kb + (long)(jt0 * 64 + r) * KV_SIZE + g * HD + c * 8,
                        &Kbuf[0][i * 2048 + wv * 512]);
        }
        int cur = 0;
        for (int jt = jt0; jt < jt1; ++jt) {
            __syncthreads();   // K[cur] landed; all prior LDS readers done

            if (jt + 1 < jt1) {   // K prefetch -> other buffer (full iter to land)
#pragma unroll
                for (int i = 0; i < 4; ++i) {
                    int s_ = i * 256 + tid;
                    int r = s_ >> 4, c = (s_ & 15) ^ (r & 15);
                    gload_lds16(kb + (long)((jt + 1) * 64 + r) * KV_SIZE + g * HD + c * 8,
                                &Kbuf[cur ^ 1][i * 2048 + wv * 512]);
                }
            }
            // V for CURRENT tile (single buffer; consumed after mid barrier)
#pragma unroll
            for (int i = 0; i < 4; ++i) {
                int s_ = i * 256 + tid;
                int r = s_ >> 3, c = (s_ & 7) ^ (r & 7);
                gload_lds16(vt + ((long)g * HD + r) * T + jt * 64 + c * 8,
                            &Vbuf[i * 2048 + wv * 512]);
            }

            // S^T = K Q^T for both q-sets, sharing K fragment loads
            floatx4 acc_s[2][4];
#pragma unroll
            for (int s = 0; s < 2; ++s)
#pragma unroll
                for (int c = 0; c < 4; ++c) acc_s[s][c] = (floatx4){0.f, 0.f, 0.f, 0.f};
#pragma unroll
            for (int kk = 0; kk < 4; ++kk) {
#pragma unroll
                for (int c = 0; c < 4; ++c) {
                    short8 ak = *(const short8*)&Kbuf[cur][(c * 16 + m) * 128 +
                                                           (((4 * kk + qd) ^ m) * 8)];
                    acc_s[0][c] = __builtin_amdgcn_mfma_f32_16x16x32_bf16(ak, aq[0][kk], acc_s[0][c], 0, 0, 0);
                    acc_s[1][c] = __builtin_amdgcn_mfma_f32_16x16x32_bf16(ak, aq[1][kk], acc_s[1][c], 0, 0, 0);
                }
            }

            // per-set online softmax + P write
#pragma unroll
            for (int s = 0; s < 2; ++s) {
                const int dg = 2 * qt + s;
                if (jt >= dg) {
                    const bool full = (jt > dg);
#pragma unroll
                    for (int c = 0; c < 4; ++c)
#pragma unroll
                        for (int r = 0; r < 4; ++r)
                            if (full || (c * 16 + qd * 4 + r > wv * 16 + m)) acc_s[s][c][r] = -1e30f;
                }
                float mx = acc_s[s][0][0];
#pragma unroll
                for (int c = 0; c < 4; ++c)
#pragma unroll
                    for (int r = 0; r < 4; ++r) mx = fmaxf(mx, acc_s[s][c][r]);
                mx = fmaxf(mx, __shfl_xor(mx, 16));
                mx = fmaxf(mx, __shfl_xor(mx, 32));
                float mnew = fmaxf(mrow[s], mx);
                float alpha = __expf(mrow[s] - mnew);
                mrow[s] = mnew;

                float pv[4][4];
                float lsum = 0.f;
#pragma unroll
                for (int c = 0; c < 4; ++c)
#pragma unroll
                    for (int r = 0; r < 4; ++r) {
                        pv[c][r] = __expf(acc_s[s][c][r] - mnew);
                        lsum += pv[c][r];
                    }
                lsum += __shfl_xor(lsum, 16);
                lsum += __shfl_xor(lsum, 32);
                lrow[s] = lrow[s] * alpha + lsum;
#pragma unroll
                for (int nb = 0; nb < 8; ++nb)
#pragma unroll
                    for (int r = 0; r < 4; ++r) acc_o[s][nb][r] *= alpha;
#pragma unroll
                for (int c = 0; c < 4; ++c) {
                    short4v pk = {(short)f2bf(pv[c][0]), (short)f2bf(pv[c][1]),
                                  (short)f2bf(pv[c][2]), (short)f2bf(pv[c][3])};
                    *(short4v*)&myP[(s * 16 + m) * 72 + c * 16 + qd * 4] = pk;
                }
            }

            __syncthreads();   // V landed (and block-wide sync)

            // PV for both sets, sharing V fragment loads
#pragma unroll
            for (int kk = 0; kk < 2; ++kk) {
                short8 pa0 = *(const short8*)&myP[m * 72 + kk * 32 + qd * 8];
                short8 pa1 = *(const short8*)&myP[(16 + m) * 72 + kk * 32 + qd * 8];
#pragma unroll
                for (int nb = 0; nb < 8; ++nb) {
                    short8 av = *(const short8*)&Vbuf[(nb * 16 + m) * 64 +
                                                      (((4 * kk + qd) ^ (m & 7)) * 8)];
                    acc_o[0][nb] = __builtin_amdgcn_mfma_f32_16x16x32_bf16(av, pa0, acc_o[0][nb], 0, 0, 0);
                    acc_o[1][nb] = __builtin_amdgcn_mfma_f32_16x16x32_bf16(av, pa1, acc_o[1][nb], 0, 0, 0);
                }
            }
            cur ^= 1;
        }

        // store partials for this unit
        const int unit = (h * 16 + qt) * 2 + half;
#pragma unroll
        for (int s = 0; s < 2; ++s) {
            const long rb = (long)unit * 128 + s * 64 + wv * 16 + m;
#pragma unroll
            for (int nb = 0; nb < 8; ++nb)
                *(floatx4*)&Opart[rb * 128 + nb * 16 + qd * 4] = acc_o[s][nb];
            if (qd == 0) {
                MLpart[rb * 2]     = mrow[s];
                MLpart[rb * 2 + 1] = lrow[s];
            }
        }
    }
}

// ---------------- combine K-split partials -> ab bf16 [t][h*128+d] ----------------
__global__ __launch_bounds__(256) void attn_combine(const float* __restrict__ Opart,
                                                    const float* __restrict__ MLpart,
                                                    unsigned short* __restrict__ ab) {
    const int tid = threadIdx.x;
    const int q = blockIdx.x * 16 + (tid >> 4);
    const int h = blockIdx.y;
    const int d0 = (tid & 15) * 8;
    const int qt = q >> 7, lr = q & 127;
    const long r0 = ((long)(h * 16 + qt) * 2) * 128 + lr;
    const long r1 = r0 + 128;
    float m0 = MLpart[r0 * 2], l0 = MLpart[r0 * 2 + 1];
    float m1 = MLpart[r1 * 2], l1 = MLpart[r1 * 2 + 1];
    float M = fmaxf(m0, m1);
    float a0 = __expf(m0 - M), a1 = __expf(m1 - M);
    float inv = 1.f / (l0 * a0 + l1 * a1);
    const float* O0 = Opart + r0 * 128 + d0;
    const float* O1 = Opart + r1 * 128 + d0;
    unsigned short outv[8];
#pragma unroll
    for (int j = 0; j < 8; j += 4) {
        float4 x0 = *(const float4*)(O0 + j);
        float4 x1 = *(const float4*)(O1 + j);
        outv[j]     = f2bf((x0.x * a0 + x1.x * a1) * inv);
        outv[j + 1] = f2bf((x0.y * a0 + x1.y * a1) * inv);
        outv[j + 2] = f2bf((x0.z * a0 + x1.z * a1) * inv);
        outv[j + 3] = f2bf((x0.w * a0 + x1.w * a1) * inv);
    }
    *(short8*)&ab[(long)q * Q_SIZE + h * HD + d0] = *(short8*)outv;
}

extern "C" void kernel_launch(void* const* d_in, const int* in_sizes, int n_in,
                              void* d_out, int out_size, void* d_ws, size_t ws_size,
                              hipStream_t stream) {
    const int* positions = (const int*)d_in[0];
    const float* hidden  = (const float*)d_in[1];
    const float* w_qkv   = (const float*)d_in[2];
    const float* w_o     = (const float*)d_in[3];
    float* out = (float*)d_out;

    char* p = (char*)d_ws;
    auto alloc = [&](size_t bytes) { char* r = p; p += (bytes + 255) & ~(size_t)255; return r; };
    float* cosT = (float*)alloc((size_t)T * 64 * 4);
    float* sinT = (float*)alloc((size_t)T * 64 * 4);
    unsigned short* hb  = (unsigned short*)alloc((size_t)T * HIDDEN * 2);
    unsigned short* wqt = (unsigned short*)alloc((size_t)QKV_N * HIDDEN * 2);
    unsigned short* wot = (unsigned short*)alloc((size_t)HIDDEN * HIDDEN * 2);
    unsigned short* qb  = (unsigned short*)alloc((size_t)T * Q_SIZE * 2);
    unsigned short* kb  = (unsigned short*)alloc((size_t)T * KV_SIZE * 2);
    unsigned short* vt  = (unsigned short*)alloc((size_t)T * KV_SIZE * 2);
    unsigned short* ab  = (unsigned short*)alloc((size_t)T * Q_SIZE * 2);
    float* Opart  = (float*)alloc((size_t)512 * 128 * 128 * 4);   // 33.5 MB
    float* MLpart = (float*)alloc((size_t)512 * 128 * 2 * 4);

    // 1) fused prep (convert + 2 transposes + cos/sin tables)
    prep_misc<<<dim3(14848), 256, 0, stream>>>(hidden, w_qkv, w_o, positions,
                                               hb, wqt, wot, cosT, sinT);
    // 2) fused qkv projection + rope -> qb (scaled), kb, vt (64x128 tiles, 768 blocks)
    gemm_qkv<<<dim3(T / 64, QKV_N / 128), 256, 0, stream>>>(hb, wqt, cosT, sinT, qb, kb, vt);
    // 3) fused causal attention (128-row blocks, dedup pairing, K-split x2)
    flash_attn<<<dim3(256), 256, 0, stream>>>(qb, kb, vt, Opart, MLpart);
    // 4) combine partials
    attn_combine<<<dim3(T / 16, NH), 256, 0, stream>>>(Opart, MLpart, ab);
    // 5) out = attn @ w_o (64x128 tiles, 512 blocks)
    gemm_out<<<dim3(T / 64, HIDDEN / 128), 256, 0, stream>>>(ab, wot, out, Q_SIZE, HIDDEN);
}